// Round 2
// baseline (1463.272 us; speedup 1.0000x reference)
//
#include <hip/hip_runtime.h>
#include <math.h>

typedef __attribute__((ext_vector_type(8))) short bf16x8;   // 8 bf16 in 4 VGPRs (MFMA frag)
typedef __attribute__((ext_vector_type(4))) float f32x4;    // MFMA C/D frag
typedef __attribute__((ext_vector_type(4))) unsigned short u16x4;
typedef __attribute__((ext_vector_type(8))) unsigned short u16x8;
typedef __attribute__((ext_vector_type(2))) unsigned int u32x2;
typedef unsigned short u16;
typedef unsigned int u32;

#define DEV __device__ __forceinline__

DEV u16 f2b(float f) {               // f32 -> bf16 RNE
  u32 u = __builtin_bit_cast(u32, f);
  u += 0x7fffu + ((u >> 16) & 1u);
  return (u16)(u >> 16);
}

#define MFMA(a, b, c) __builtin_amdgcn_mfma_f32_16x16x32_bf16(a, b, c, 0, 0, 0)
// async global->LDS, 16B per lane. LDS dest must be wave-uniform-base + lane*16.
#define G2L(g, l)                                                              \
  __builtin_amdgcn_global_load_lds((__attribute__((address_space(1))) void*)(g), \
                                   (__attribute__((address_space(3))) void*)(l), \
                                   16, 0, 0)

// ---------------------------------------------------------------------------
// LayerNorm over rows of 2048. One block per row, 256 threads x 8 elems.
// ---------------------------------------------------------------------------
template <bool WF32>
__global__ __launch_bounds__(256) void k_ln(const float* __restrict__ in,
                                            const float* __restrict__ gw,
                                            const float* __restrict__ bw,
                                            u16* __restrict__ outb,
                                            float* __restrict__ outf) {
  int row = blockIdx.x, t = threadIdx.x;
  const float* p = in + (size_t)row * 2048 + t * 8;
  float4 v0 = *(const float4*)p;
  float4 v1 = *(const float4*)(p + 4);
  float xv[8] = {v0.x, v0.y, v0.z, v0.w, v1.x, v1.y, v1.z, v1.w};
  float s = 0.f, q = 0.f;
#pragma unroll
  for (int i = 0; i < 8; ++i) { s += xv[i]; q += xv[i] * xv[i]; }
#pragma unroll
  for (int o = 32; o > 0; o >>= 1) {
    s += __shfl_down(s, o);
    q += __shfl_down(q, o);
  }
  __shared__ float rs[4], rq[4];
  int lane = t & 63, w = t >> 6;
  if (lane == 0) { rs[w] = s; rq[w] = q; }
  __syncthreads();
  s = rs[0] + rs[1] + rs[2] + rs[3];
  q = rq[0] + rq[1] + rq[2] + rq[3];
  float mean = s * (1.0f / 2048.0f);
  float inv = rsqrtf(q * (1.0f / 2048.0f) - mean * mean + 1e-5f);
  float4 g0 = *(const float4*)(gw + t * 8);
  float4 g1 = *(const float4*)(gw + t * 8 + 4);
  float4 b0 = *(const float4*)(bw + t * 8);
  float4 b1 = *(const float4*)(bw + t * 8 + 4);
  float gv[8] = {g0.x, g0.y, g0.z, g0.w, g1.x, g1.y, g1.z, g1.w};
  float bv[8] = {b0.x, b0.y, b0.z, b0.w, b1.x, b1.y, b1.z, b1.w};
  float y[8];
  u16x8 ob;
#pragma unroll
  for (int i = 0; i < 8; ++i) {
    y[i] = (xv[i] - mean) * inv * gv[i] + bv[i];
    ob[i] = f2b(y[i]);
  }
  *(u16x8*)(outb + (size_t)row * 2048 + t * 8) = ob;
  if (WF32) {
    float* o = outf + (size_t)row * 2048 + t * 8;
    *(float4*)o = make_float4(y[0], y[1], y[2], y[3]);
    *(float4*)(o + 4) = make_float4(y[4], y[5], y[6], y[7]);
  }
}

// ---------------------------------------------------------------------------
// Transpose + f32->bf16: in K x N f32 row-major -> out N x K bf16 row-major.
// grid (N/32, K/32), 256 threads.
// ---------------------------------------------------------------------------
__global__ __launch_bounds__(256) void k_twt(const float* __restrict__ in,
                                             u16* __restrict__ out, int K, int N) {
  __shared__ float tl[32][33];
  int t = threadIdx.x, r = t >> 3, c = (t & 7) * 4;
  size_t n0 = (size_t)blockIdx.x * 32, k0 = (size_t)blockIdx.y * 32;
  float4 v = *(const float4*)(in + (k0 + r) * N + n0 + c);
  tl[r][c] = v.x; tl[r][c + 1] = v.y; tl[r][c + 2] = v.z; tl[r][c + 3] = v.w;
  __syncthreads();
  u16x4 o = {f2b(tl[c][r]), f2b(tl[c + 1][r]), f2b(tl[c + 2][r]), f2b(tl[c + 3][r])};
  *(u16x4*)(out + (n0 + r) * K + k0 + c) = o;
}

// ---------------------------------------------------------------------------
// V (bf16, [B*S][D] with col = h*128+d) -> VT [(b*16+h)*128 + d][2048]
// grid (64, 4, 32) = (s-tiles, d-tiles, b*h), 256 threads.
// ---------------------------------------------------------------------------
__global__ __launch_bounds__(256) void k_vt(const u16* __restrict__ v,
                                            u16* __restrict__ vt) {
  __shared__ u16 tl[32][36];
  int t = threadIdx.x, r = t >> 3, c = (t & 7) * 4;
  int s0 = blockIdx.x * 32, d0 = blockIdx.y * 32, bh = blockIdx.z;
  int b = bh >> 4, h = bh & 15;
  u16x4 x = *(const u16x4*)(v + (size_t)(b * 2048 + s0 + r) * 2048 + h * 128 + d0 + c);
  tl[r][c] = x[0]; tl[r][c + 1] = x[1]; tl[r][c + 2] = x[2]; tl[r][c + 3] = x[3];
  __syncthreads();
  u16x4 o = {tl[c][r], tl[c + 1][r], tl[c + 2][r], tl[c + 3][r]};
  *(u16x4*)(vt + (size_t)(bh * 128 + d0 + r) * 2048 + s0 + c) = o;
}

// ---------------------------------------------------------------------------
// rowvec[n] = pemb[trait] @ dw[D: , n] (+ db[n]); dec bias row. grid (8, 32).
// ---------------------------------------------------------------------------
__global__ __launch_bounds__(256) void k_rowvec(const float* __restrict__ pemb,
                                                const int* __restrict__ trait,
                                                const float* __restrict__ dw,
                                                const float* __restrict__ db,
                                                float* __restrict__ rv) {
  int n = blockIdx.x * 256 + threadIdx.x;
  int k0 = blockIdx.y * 64;
  const float* pe = pemb + (size_t)trait[0] * 2048;
  float acc = 0.f;
#pragma unroll 4
  for (int k = 0; k < 64; ++k)
    acc = fmaf(pe[k0 + k], dw[(size_t)(2048 + k0 + k) * 2048 + n], acc);
  if (blockIdx.y == 0) acc += db[n];
  atomicAdd(rv + n, acc);
}

// ---------------------------------------------------------------------------
// bf16 GEMM, C = A(MxK) @ Bt(NxK)^T. Exact m97 structure: 128x128 tile, BK=32,
// 4 waves (2x2, 64x64 each, 4x4 frags of 16x16x32 MFMA), single-buffer LDS,
// global_load_lds width 16, LINEAR staging (no swizzle — m97-proven).
// EPI: 0 = bf16 store, 1 = gelu(x+bias) bf16 store, 2 = f32 (+bias)(+res).
// ---------------------------------------------------------------------------
template <int EPI, bool HB, bool HR>
__global__ __launch_bounds__(256) void k_gemm(const u16* __restrict__ A,
                                              const u16* __restrict__ Bt,
                                              void* __restrict__ outv,
                                              const float* __restrict__ bias,
                                              const float* __restrict__ res,
                                              int N, int K) {
  __shared__ __align__(16) u16 sm[8192];  // A tile bytes [0,8192), B tile [8192,16384)
  char* smc = (char*)sm;
  int t = threadIdx.x, lane = t & 63, w = t >> 6;
  int l15 = lane & 15, q4 = lane >> 4;
  int wr = w >> 1, wc = w & 1;
  int m0 = blockIdx.x * 128, n0 = blockIdx.y * 128;
  // staging: thread t writes LDS bytes t*16; row = t>>2, chunk = t&3 (linear).
  int srow = t >> 2;
  const u16* gA0 = A + (size_t)(m0 + srow) * K + (t & 3) * 8;
  const u16* gA1 = gA0 + (size_t)64 * K;
  const u16* gB0 = Bt + (size_t)(n0 + srow) * K + (t & 3) * 8;
  const u16* gB1 = gB0 + (size_t)64 * K;
  int offA[4], offB[4];
#pragma unroll
  for (int f = 0; f < 4; ++f) {
    offA[f] = (wr * 64 + f * 16 + l15) * 64 + q4 * 16;
    offB[f] = 8192 + (wc * 64 + f * 16 + l15) * 64 + q4 * 16;
  }
  f32x4 acc[4][4];
#pragma unroll
  for (int m = 0; m < 4; ++m)
#pragma unroll
    for (int n = 0; n < 4; ++n) acc[m][n] = (f32x4){0.f, 0.f, 0.f, 0.f};

  int nkt = K >> 5;
  for (int kt = 0; kt < nkt; ++kt) {
    int ko = kt * 32;
    __syncthreads();
    G2L(gA0 + ko, smc + t * 16);
    G2L(gA1 + ko, smc + 4096 + t * 16);
    G2L(gB0 + ko, smc + 8192 + t * 16);
    G2L(gB1 + ko, smc + 12288 + t * 16);
    __syncthreads();
    bf16x8 av[4], bv[4];
#pragma unroll
    for (int f = 0; f < 4; ++f) av[f] = *(const bf16x8*)(smc + offA[f]);
#pragma unroll
    for (int f = 0; f < 4; ++f) bv[f] = *(const bf16x8*)(smc + offB[f]);
#pragma unroll
    for (int m = 0; m < 4; ++m)
#pragma unroll
      for (int n = 0; n < 4; ++n) acc[m][n] = MFMA(av[m], bv[n], acc[m][n]);
  }

  // epilogue: C/D frag: col = l15, row = q4*4 + reg (m89-verified mapping)
  int rbase = m0 + wr * 64 + q4 * 4;
  int cbase = n0 + wc * 64 + l15;
#pragma unroll
  for (int n = 0; n < 4; ++n) {
    int col = cbase + n * 16;
    float bb = HB ? bias[col] : 0.f;
#pragma unroll
    for (int m = 0; m < 4; ++m) {
      int row0 = rbase + m * 16;
#pragma unroll
      for (int r = 0; r < 4; ++r) {
        size_t idx = (size_t)(row0 + r) * N + col;
        float val = acc[m][n][r];
        if constexpr (EPI == 0) {
          ((u16*)outv)[idx] = f2b(val);
        } else if constexpr (EPI == 1) {
          val += bb;
          val = 0.5f * val * (1.f + erff(val * 0.70710678118654752f));  // exact gelu
          ((u16*)outv)[idx] = f2b(val);
        } else {
          val += bb;
          if (HR) val += res[idx];
          ((float*)outv)[idx] = val;
        }
      }
    }
  }
}

// ---------------------------------------------------------------------------
// Flash attention, bf16. grid (16 q-tiles, 32 b*h), 256 threads = 4 waves,
// each wave owns 32 q-rows. Swapped QK^T (mfma(K,Q) -> S^T, col = q) so the
// k-axis softmax reduce is 2 shfl_xor. LINEAR K/V staging (no swizzle).
// Explicit barriers around per-wave P/scale LDS staging.
// ---------------------------------------------------------------------------
__global__ __launch_bounds__(256) void k_attn(const u16* __restrict__ Q,
                                              const u16* __restrict__ Kg,
                                              const u16* __restrict__ VT,
                                              u16* __restrict__ O) {
  __shared__ __align__(16) char sm[27648];
  char* sK = sm;            // [32][128] bf16 (K rows), 256B rows, linear chunks
  char* sV = sm + 8192;     // [128][32] bf16 (V^T rows), 64B rows, linear chunks
  int t = threadIdx.x, lane = t & 63, w = t >> 6;
  int l15 = lane & 15, q4 = lane >> 4;
  int bh = blockIdx.y;
  int b = bh >> 4, h = bh & 15;
  int q0 = blockIdx.x * 128 + w * 32;
  char* sP = sm + 16384 + w * 2560;             // per-wave P: 32 rows x 80B
  float* sSc = (float*)(sm + 26624 + w * 128);  // per-wave 32 floats
  const float cs = 0.08838834764831845f;  // 1/sqrt(128)
  const u16* Kbase = Kg + (size_t)(b * 2048) * 2048 + h * 128;
  const u16* Vbase = VT + (size_t)(bh * 128) * 2048;
  const u16* Qbase = Q + (size_t)(b * 2048) * 2048 + h * 128;

  bf16x8 qf[2][4];  // B-frags of Q: col q = fn*16+l15, k(d) = kit*32 + q4*8..
#pragma unroll
  for (int fn = 0; fn < 2; ++fn)
#pragma unroll
    for (int kit = 0; kit < 4; ++kit)
      qf[fn][kit] = *(const bf16x8*)(Qbase + (size_t)(q0 + fn * 16 + l15) * 2048 +
                                     kit * 32 + q4 * 8);
  f32x4 oacc[2][8];
#pragma unroll
  for (int fm = 0; fm < 2; ++fm)
#pragma unroll
    for (int fn = 0; fn < 8; ++fn) oacc[fm][fn] = (f32x4){0.f, 0.f, 0.f, 0.f};
  float mrun[2] = {-3e38f, -3e38f}, lrun[2] = {0.f, 0.f};

  int kv_s = t >> 4;   // K staging row (within 16-row half-tile), chunk = t&15
  int d_s = t >> 2;    // V staging row, chunk = t&3

  for (int kv0 = 0; kv0 < 2048; kv0 += 32) {
    __syncthreads();
    G2L(Kbase + (size_t)(kv0 + kv_s) * 2048 + (t & 15) * 8, sK + t * 16);
    G2L(Kbase + (size_t)(kv0 + 16 + kv_s) * 2048 + (t & 15) * 8, sK + 4096 + t * 16);
    G2L(Vbase + (size_t)d_s * 2048 + kv0 + (t & 3) * 8, sV + t * 16);
    G2L(Vbase + (size_t)(64 + d_s) * 2048 + kv0 + (t & 3) * 8, sV + 4096 + t * 16);
    __syncthreads();

    // S^T = K @ Q^T : D[kv][q], frag col = q = l15, row = q4*4+reg (+fm*16)
    f32x4 st[2][2];
#pragma unroll
    for (int fm = 0; fm < 2; ++fm)
#pragma unroll
      for (int fn = 0; fn < 2; ++fn) st[fm][fn] = (f32x4){0.f, 0.f, 0.f, 0.f};
#pragma unroll
    for (int kit = 0; kit < 4; ++kit) {
      int cw = kit * 4 + q4;
      bf16x8 kf0 = *(const bf16x8*)(sK + l15 * 256 + cw * 16);
      bf16x8 kf1 = *(const bf16x8*)(sK + (16 + l15) * 256 + cw * 16);
      st[0][0] = MFMA(kf0, qf[0][kit], st[0][0]);
      st[0][1] = MFMA(kf0, qf[1][kit], st[0][1]);
      st[1][0] = MFMA(kf1, qf[0][kit], st[1][0]);
      st[1][1] = MFMA(kf1, qf[1][kit], st[1][1]);
    }

    // online softmax per q-column (fn picks which q 16-block)
#pragma unroll
    for (int fn = 0; fn < 2; ++fn) {
      float mx = st[0][fn][0];
#pragma unroll
      for (int r = 1; r < 4; ++r) mx = fmaxf(mx, st[0][fn][r]);
#pragma unroll
      for (int r = 0; r < 4; ++r) mx = fmaxf(mx, st[1][fn][r]);
      mx = fmaxf(mx, __shfl_xor(mx, 16));
      mx = fmaxf(mx, __shfl_xor(mx, 32));
      float mnew = fmaxf(mrun[fn], mx);
      float sc = __expf(cs * (mrun[fn] - mnew));
      float psum = 0.f;
      u16 pb[8];
#pragma unroll
      for (int fm = 0; fm < 2; ++fm)
#pragma unroll
        for (int r = 0; r < 4; ++r) {
          float p = __expf(cs * (st[fm][fn][r] - mnew));
          psum += p;
          pb[fm * 4 + r] = f2b(p);
        }
      psum += __shfl_xor(psum, 16);
      psum += __shfl_xor(psum, 32);
      lrun[fn] = lrun[fn] * sc + psum;
      mrun[fn] = mnew;
      int qr = fn * 16 + l15;
      u32x2 w0 = {(u32)pb[0] | ((u32)pb[1] << 16), (u32)pb[2] | ((u32)pb[3] << 16)};
      u32x2 w1 = {(u32)pb[4] | ((u32)pb[5] << 16), (u32)pb[6] | ((u32)pb[7] << 16)};
      *(u32x2*)(sP + qr * 80 + q4 * 8) = w0;        // P[q][k: q4*4..]
      *(u32x2*)(sP + qr * 80 + 32 + q4 * 8) = w1;   // P[q][k: 16+q4*4..]
      if (q4 == 0) sSc[qr] = sc;
    }
    __syncthreads();  // make sP/sSc writes visible (defensive: within-wave DS order)

    // rescale accumulators (scale indexed by acc's row q = fm*16 + q4*4 + r)
#pragma unroll
    for (int fm = 0; fm < 2; ++fm) {
      f32x4 sv_ = *(const f32x4*)((char*)sSc + fm * 64 + q4 * 16);
#pragma unroll
      for (int fn = 0; fn < 8; ++fn)
#pragma unroll
        for (int r = 0; r < 4; ++r) oacc[fm][fn][r] *= sv_[r];
    }
    // PV: out[q][d] += P @ V ; A-frag = P rows, B-frag = VT rows
    bf16x8 pa0 = *(const bf16x8*)(sP + l15 * 80 + q4 * 16);
    bf16x8 pa1 = *(const bf16x8*)(sP + (16 + l15) * 80 + q4 * 16);
#pragma unroll
    for (int fn = 0; fn < 8; ++fn) {
      bf16x8 vv = *(const bf16x8*)(sV + (fn * 16 + l15) * 64 + q4 * 16);
      oacc[0][fn] = MFMA(pa0, vv, oacc[0][fn]);
      oacc[1][fn] = MFMA(pa1, vv, oacc[1][fn]);
    }
  }

  if (q4 == 0) { sSc[l15] = lrun[0]; sSc[16 + l15] = lrun[1]; }
  __syncthreads();  // defensive: order lrun writes before lv reads
  f32x4 lv0 = *(const f32x4*)((char*)sSc + q4 * 16);
  f32x4 lv1 = *(const f32x4*)((char*)sSc + 64 + q4 * 16);
#pragma unroll
  for (int fm = 0; fm < 2; ++fm) {
    f32x4 lv = fm ? lv1 : lv0;
#pragma unroll
    for (int r = 0; r < 4; ++r) {
      int qg = q0 + fm * 16 + q4 * 4 + r;
      float inv = 1.f / lv[r];
#pragma unroll
      for (int fn = 0; fn < 8; ++fn)
        O[(size_t)(b * 2048 + qg) * 2048 + h * 128 + fn * 16 + l15] =
            f2b(oacc[fm][fn][r] * inv);
    }
  }
}

// ---------------------------------------------------------------------------
extern "C" void kernel_launch(void* const* d_in, const int* in_sizes, int n_in,
                              void* d_out, int out_size, void* d_ws, size_t ws_size,
                              hipStream_t stream) {
  (void)in_sizes; (void)n_in; (void)out_size; (void)ws_size;
  const float* x0 = (const float*)d_in[0];
  const int* trait = (const int*)d_in[2];
  const float* wq = (const float*)d_in[3];
  const float* wk = (const float*)d_in[4];
  const float* wv = (const float*)d_in[5];
  const float* wo = (const float*)d_in[6];
  const float* g1 = (const float*)d_in[7];
  const float* b1 = (const float*)d_in[8];
  const float* g2 = (const float*)d_in[9];
  const float* b2 = (const float*)d_in[10];
  const float* rw1 = (const float*)d_in[11];
  const float* rb1 = (const float*)d_in[12];
  const float* rw2 = (const float*)d_in[13];
  const float* rb2 = (const float*)d_in[14];
  const float* rg = (const float*)d_in[15];
  const float* rb = (const float*)d_in[16];
  const float* pemb = (const float*)d_in[17];
  const float* dw = (const float*)d_in[18];
  const float* db = (const float*)d_in[19];
  const float* wg = (const float*)d_in[20];
  const float* wb = (const float*)d_in[21];
  const float* mw1 = (const float*)d_in[22];
  const float* mb1 = (const float*)d_in[23];
  const float* mw2 = (const float*)d_in[24];
  const float* mb2 = (const float*)d_in[25];

  char* ws = (char*)d_ws;
  // arena (bytes): A1 16.78M | B1..B4 4x16.78M | X1 33.55M | H2F 33.55M | WA 33.55M | RV
  u16* A1 = (u16*)ws;
  u16* B1 = (u16*)(ws + 16777216);
  u16* B2 = (u16*)(ws + 33554432);
  u16* B3 = (u16*)(ws + 50331648);
  u16* B4 = (u16*)(ws + 67108864);
  float* X1 = (float*)(ws + 83886080);
  float* H2F = (float*)(ws + 117440512);
  u16* WA = (u16*)(ws + 150994944);
  float* RV = (float*)(ws + 184549376);

  dim3 blk(256);
  // h1 = LN(x0)
  k_ln<false><<<4096, blk, 0, stream>>>(x0, g1, b1, A1, nullptr);
  // q, k, v
  k_twt<<<dim3(64, 64), blk, 0, stream>>>(wq, WA, 2048, 2048);
  k_gemm<0, false, false><<<dim3(32, 16), blk, 0, stream>>>(A1, WA, B1, nullptr, nullptr, 2048, 2048);
  k_twt<<<dim3(64, 64), blk, 0, stream>>>(wk, WA, 2048, 2048);
  k_gemm<0, false, false><<<dim3(32, 16), blk, 0, stream>>>(A1, WA, B2, nullptr, nullptr, 2048, 2048);
  k_twt<<<dim3(64, 64), blk, 0, stream>>>(wv, WA, 2048, 2048);
  k_gemm<0, false, false><<<dim3(32, 16), blk, 0, stream>>>(A1, WA, B3, nullptr, nullptr, 2048, 2048);
  // per-head V^T, then flash attention -> A1 (bf16)
  k_vt<<<dim3(64, 4, 32), blk, 0, stream>>>(B3, B4);
  k_attn<<<dim3(16, 32), blk, 0, stream>>>(B1, B2, B4, A1);
  // x1 = x0 + attn @ wo
  k_twt<<<dim3(64, 64), blk, 0, stream>>>(wo, WA, 2048, 2048);
  k_gemm<2, false, true><<<dim3(32, 16), blk, 0, stream>>>(A1, WA, X1, nullptr, x0, 2048, 2048);
  // h2 = LN(x1) (bf16 + f32)
  k_ln<true><<<4096, blk, 0, stream>>>(X1, g2, b2, A1, H2F);
  // t1 = gelu(h2 @ rw1 + rb1)
  k_twt<<<dim3(128, 64), blk, 0, stream>>>(rw1, WA, 2048, 4096);
  k_gemm<1, true, false><<<dim3(32, 32), blk, 0, stream>>>(A1, WA, B1, rb1, nullptr, 4096, 2048);
  // H2F = h2 + t1 @ rw2 + rb2 (in place), then h3 = LN(.) (bf16 + f32 in place)
  k_twt<<<dim3(64, 128), blk, 0, stream>>>(rw2, WA, 4096, 2048);
  k_gemm<2, true, true><<<dim3(32, 16), blk, 0, stream>>>(B1, WA, H2F, rb2, H2F, 2048, 4096);
  k_ln<true><<<4096, blk, 0, stream>>>(H2F, rg, rb, A1, H2F);
  // dec bias row: RV = pemb[trait] @ dw[D:] + db
  hipMemsetAsync(RV, 0, 2048 * sizeof(float), stream);
  k_rowvec<<<dim3(8, 32), blk, 0, stream>>>(pemb, trait, dw, db, RV);
  // H2F = h3 + h3 @ dw[:D] + RV (in place), then h4 = LN(.)
  k_twt<<<dim3(64, 64), blk, 0, stream>>>(dw, WA, 2048, 2048);
  k_gemm<2, true, true><<<dim3(32, 16), blk, 0, stream>>>(A1, WA, H2F, RV, H2F, 2048, 2048);
  k_ln<false><<<4096, blk, 0, stream>>>(H2F, wg, wb, A1, nullptr);
  // out = x1 + gelu(h4 @ mw1 + mb1) @ mw2 + mb2
  k_twt<<<dim3(256, 64), blk, 0, stream>>>(mw1, WA, 2048, 8192);
  k_gemm<1, true, false><<<dim3(32, 64), blk, 0, stream>>>(A1, WA, B1, mb1, nullptr, 8192, 2048);
  k_twt<<<dim3(64, 256), blk, 0, stream>>>(mw2, WA, 8192, 2048);
  k_gemm<2, true, true><<<dim3(32, 16), blk, 0, stream>>>(B1, WA, (float*)d_out, mb2, X1, 2048, 8192);
}

// Round 4
// 1442.885 us; speedup vs baseline: 1.0141x; 1.0141x over previous
//
#include <hip/hip_runtime.h>
#include <math.h>

typedef __attribute__((ext_vector_type(8))) short bf16x8;   // 8 bf16 in 4 VGPRs (MFMA frag)
typedef __attribute__((ext_vector_type(4))) float f32x4;    // MFMA C/D frag
typedef __attribute__((ext_vector_type(4))) unsigned short u16x4;
typedef __attribute__((ext_vector_type(8))) unsigned short u16x8;
typedef __attribute__((ext_vector_type(2))) unsigned int u32x2;
typedef unsigned short u16;
typedef unsigned int u32;

#define DEV __device__ __forceinline__

DEV u16 f2b(float f) {               // f32 -> bf16 RNE
  u32 u = __builtin_bit_cast(u32, f);
  u += 0x7fffu + ((u >> 16) & 1u);
  return (u16)(u >> 16);
}

#define MFMA(a, b, c) __builtin_amdgcn_mfma_f32_16x16x32_bf16(a, b, c, 0, 0, 0)
// async global->LDS, 16B per lane. LDS dest must be wave-uniform-base + lane*16.
#define G2L(g, l)                                                              \
  __builtin_amdgcn_global_load_lds((__attribute__((address_space(1))) void*)(g), \
                                   (__attribute__((address_space(3))) void*)(l), \
                                   16, 0, 0)

// ---------------------------------------------------------------------------
// LayerNorm over rows of 2048. One block per row, 256 threads x 8 elems.
// ---------------------------------------------------------------------------
template <bool WF32>
__global__ __launch_bounds__(256) void k_ln(const float* __restrict__ in,
                                            const float* __restrict__ gw,
                                            const float* __restrict__ bw,
                                            u16* __restrict__ outb,
                                            float* __restrict__ outf) {
  int row = blockIdx.x, t = threadIdx.x;
  const float* p = in + (size_t)row * 2048 + t * 8;
  float4 v0 = *(const float4*)p;
  float4 v1 = *(const float4*)(p + 4);
  float xv[8] = {v0.x, v0.y, v0.z, v0.w, v1.x, v1.y, v1.z, v1.w};
  float s = 0.f, q = 0.f;
#pragma unroll
  for (int i = 0; i < 8; ++i) { s += xv[i]; q += xv[i] * xv[i]; }
#pragma unroll
  for (int o = 32; o > 0; o >>= 1) {
    s += __shfl_down(s, o);
    q += __shfl_down(q, o);
  }
  __shared__ float rs[4], rq[4];
  int lane = t & 63, w = t >> 6;
  if (lane == 0) { rs[w] = s; rq[w] = q; }
  __syncthreads();
  s = rs[0] + rs[1] + rs[2] + rs[3];
  q = rq[0] + rq[1] + rq[2] + rq[3];
  float mean = s * (1.0f / 2048.0f);
  float inv = rsqrtf(q * (1.0f / 2048.0f) - mean * mean + 1e-5f);
  float4 g0 = *(const float4*)(gw + t * 8);
  float4 g1 = *(const float4*)(gw + t * 8 + 4);
  float4 b0 = *(const float4*)(bw + t * 8);
  float4 b1 = *(const float4*)(bw + t * 8 + 4);
  float gv[8] = {g0.x, g0.y, g0.z, g0.w, g1.x, g1.y, g1.z, g1.w};
  float bv[8] = {b0.x, b0.y, b0.z, b0.w, b1.x, b1.y, b1.z, b1.w};
  float y[8];
  u16x8 ob;
#pragma unroll
  for (int i = 0; i < 8; ++i) {
    y[i] = (xv[i] - mean) * inv * gv[i] + bv[i];
    ob[i] = f2b(y[i]);
  }
  *(u16x8*)(outb + (size_t)row * 2048 + t * 8) = ob;
  if (WF32) {
    float* o = outf + (size_t)row * 2048 + t * 8;
    *(float4*)o = make_float4(y[0], y[1], y[2], y[3]);
    *(float4*)(o + 4) = make_float4(y[4], y[5], y[6], y[7]);
  }
}

// ---------------------------------------------------------------------------
// Transpose + f32->bf16: in K x N f32 row-major -> out N x K bf16 row-major.
// grid (N/32, K/32), 256 threads.
// ---------------------------------------------------------------------------
__global__ __launch_bounds__(256) void k_twt(const float* __restrict__ in,
                                             u16* __restrict__ out, int K, int N) {
  __shared__ float tl[32][33];
  int t = threadIdx.x, r = t >> 3, c = (t & 7) * 4;
  size_t n0 = (size_t)blockIdx.x * 32, k0 = (size_t)blockIdx.y * 32;
  float4 v = *(const float4*)(in + (k0 + r) * N + n0 + c);
  tl[r][c] = v.x; tl[r][c + 1] = v.y; tl[r][c + 2] = v.z; tl[r][c + 3] = v.w;
  __syncthreads();
  u16x4 o = {f2b(tl[c][r]), f2b(tl[c + 1][r]), f2b(tl[c + 2][r]), f2b(tl[c + 3][r])};
  *(u16x4*)(out + (n0 + r) * K + k0 + c) = o;
}

// ---------------------------------------------------------------------------
// V (bf16, [B*S][D] with col = h*128+d) -> VT [(b*16+h)*128 + d][2048]
// grid (64, 4, 32) = (s-tiles, d-tiles, b*h), 256 threads.
// ---------------------------------------------------------------------------
__global__ __launch_bounds__(256) void k_vt(const u16* __restrict__ v,
                                            u16* __restrict__ vt) {
  __shared__ u16 tl[32][36];
  int t = threadIdx.x, r = t >> 3, c = (t & 7) * 4;
  int s0 = blockIdx.x * 32, d0 = blockIdx.y * 32, bh = blockIdx.z;
  int b = bh >> 4, h = bh & 15;
  u16x4 x = *(const u16x4*)(v + (size_t)(b * 2048 + s0 + r) * 2048 + h * 128 + d0 + c);
  tl[r][c] = x[0]; tl[r][c + 1] = x[1]; tl[r][c + 2] = x[2]; tl[r][c + 3] = x[3];
  __syncthreads();
  u16x4 o = {tl[c][r], tl[c + 1][r], tl[c + 2][r], tl[c + 3][r]};
  *(u16x4*)(vt + (size_t)(bh * 128 + d0 + r) * 2048 + s0 + c) = o;
}

// ---------------------------------------------------------------------------
// rowvec[n] = pemb[trait] @ dw[D: , n] (+ db[n]); dec bias row. grid (8, 32).
// ---------------------------------------------------------------------------
__global__ __launch_bounds__(256) void k_rowvec(const float* __restrict__ pemb,
                                                const int* __restrict__ trait,
                                                const float* __restrict__ dw,
                                                const float* __restrict__ db,
                                                float* __restrict__ rv) {
  int n = blockIdx.x * 256 + threadIdx.x;
  int k0 = blockIdx.y * 64;
  const float* pe = pemb + (size_t)trait[0] * 2048;
  float acc = 0.f;
#pragma unroll 4
  for (int k = 0; k < 64; ++k)
    acc = fmaf(pe[k0 + k], dw[(size_t)(2048 + k0 + k) * 2048 + n], acc);
  if (blockIdx.y == 0) acc += db[n];
  atomicAdd(rv + n, acc);
}

// ---------------------------------------------------------------------------
// Deep-pipelined bf16 GEMM, C = A(MxK) @ Bt(NxK)^T.
// BM x 256 tile, BK=32, 512 threads = 8 waves (2M x 4N). Triple-buffered LDS
// (3 x TBYTES), prefetch 2 K-tiles ahead via global_load_lds; counted
// s_waitcnt vmcnt(2L) at tile boundary (never 0 in steady state); 2 raw
// s_barriers per tile. Chunk-XOR swizzle f(row)=(row+(row>>2))&3 on 16B
// chunks: frag ds_read_b128 conflicts <= 2-way per phase. Write side uses
// pre-swizzled GLOBAL source + linear LDS dest (rule 21).
// EPI: 0 = bf16 store, 1 = gelu(x+bias) bf16 store, 2 = f32 (+bias)(+res).
// ---------------------------------------------------------------------------
template <int EPI, bool HB, bool HR, int BM>
__global__ __launch_bounds__(512, 2) void k_gemm8(const u16* __restrict__ A,
                                                  const u16* __restrict__ Bt,
                                                  void* __restrict__ outv,
                                                  const float* __restrict__ bias,
                                                  const float* __restrict__ res,
                                                  int N, int K) {
  constexpr int ABYTES = BM * 32 * 2;            // 16KB (BM=256) or 8KB (BM=128)
  constexpr int TBYTES = ABYTES + 256 * 32 * 2;  // + B tile 16KB
  constexpr int LA = ABYTES / 8192;              // G2L insts for A per tile
  constexpr int L = LA + 2;                      // total G2L per tile (4 or 3)
  constexpr int MR = BM / 32;                    // M-frags per wave (8 or 4)
  __shared__ __align__(16) char smc[3 * TBYTES];
  int t = threadIdx.x, lane = t & 63, w = t >> 6;
  int l15 = lane & 15, q4 = lane >> 4;
  int wr = w >> 2, wc = w & 3;                   // 2 x 4 wave grid
  int m0 = blockIdx.x * BM, n0 = blockIdx.y * 256;
  int swz = (l15 + (l15 >> 2)) & 3;

  // staging sources: slot s = inst*512 + t -> row s>>2, stored-chunk s&3;
  // global chunk = stored ^ f(row) so that read-side XOR recovers identity.
  int r0 = t >> 2, c0 = (t & 3) ^ ((r0 + (r0 >> 2)) & 3);
  int r1 = (512 + t) >> 2, c1 = (t & 3) ^ ((r1 + (r1 >> 2)) & 3);
  const u16* gA0 = A + (size_t)(m0 + r0) * K + c0 * 8;
  const u16* gA1 = A + (size_t)(m0 + (LA == 2 ? r1 : r0)) * K + c1 * 8;  // LA==1: unused
  const u16* gB0 = Bt + (size_t)(n0 + r0) * K + c0 * 8;
  const u16* gB1 = Bt + (size_t)(n0 + r1) * K + c1 * 8;

#define ISSUE(ktile, bb)                                                       \
  {                                                                            \
    const int _ko = (ktile) * 32;                                              \
    char* _dst = smc + (bb) * TBYTES + t * 16;                                 \
    if constexpr (LA == 2) {                                                   \
      G2L(gA0 + _ko, _dst);                                                    \
      G2L(gA1 + _ko, _dst + 8192);                                             \
      G2L(gB0 + _ko, _dst + 16384);                                            \
      G2L(gB1 + _ko, _dst + 24576);                                            \
    } else {                                                                   \
      G2L(gA0 + _ko, _dst);                                                    \
      G2L(gB0 + _ko, _dst + 8192);                                             \
      G2L(gB1 + _ko, _dst + 16384);                                            \
    }                                                                          \
  }

  // frag read offsets (A: row = wr*BM/2 + m*16 + l15; k-chunk q4, swizzled)
  int offA[MR], offB[4];
#pragma unroll
  for (int m = 0; m < MR; ++m)
    offA[m] = (wr * (BM / 2) + m * 16 + l15) * 64 + ((q4 ^ swz) * 16);
#pragma unroll
  for (int n = 0; n < 4; ++n)
    offB[n] = ABYTES + (wc * 64 + n * 16 + l15) * 64 + ((q4 ^ swz) * 16);

  f32x4 acc[MR][4];
#pragma unroll
  for (int m = 0; m < MR; ++m)
#pragma unroll
    for (int n = 0; n < 4; ++n) acc[m][n] = (f32x4){0.f, 0.f, 0.f, 0.f};

  const int nt = K >> 5;
  ISSUE(0, 0);
  ISSUE(1, 1);
  for (int kt = 0; kt < nt; ++kt) {
    int bc = kt % 3;
    if (kt + 2 < nt) {
      ISSUE(kt + 2, (kt + 2) % 3);
      if constexpr (L == 4) { asm volatile("s_waitcnt vmcnt(8)" ::: "memory"); }
      else                  { asm volatile("s_waitcnt vmcnt(6)" ::: "memory"); }
    } else if (kt + 1 < nt) {
      if constexpr (L == 4) { asm volatile("s_waitcnt vmcnt(4)" ::: "memory"); }
      else                  { asm volatile("s_waitcnt vmcnt(3)" ::: "memory"); }
    } else {
      asm volatile("s_waitcnt vmcnt(0)" ::: "memory");
    }
    __builtin_amdgcn_s_barrier();       // all waves: tile kt fully in LDS
    asm volatile("" ::: "memory");
    const char* bp = smc + bc * TBYTES;
    bf16x8 av[MR], bv[4];
#pragma unroll
    for (int m = 0; m < MR; ++m) av[m] = *(const bf16x8*)(bp + offA[m]);
#pragma unroll
    for (int n = 0; n < 4; ++n) bv[n] = *(const bf16x8*)(bp + offB[n]);
    __builtin_amdgcn_s_setprio(1);
#pragma unroll
    for (int m = 0; m < MR; ++m)
#pragma unroll
      for (int n = 0; n < 4; ++n) acc[m][n] = MFMA(av[m], bv[n], acc[m][n]);
    __builtin_amdgcn_s_setprio(0);
    asm volatile("s_waitcnt lgkmcnt(0)" ::: "memory");  // reads drained
    __builtin_amdgcn_s_barrier();       // all waves done reading buf bc
    asm volatile("" ::: "memory");
  }
#undef ISSUE

  // epilogue: C/D frag: col = l15, row = q4*4 + reg (m89-verified mapping)
  int rbase = m0 + wr * (BM / 2) + q4 * 4;
  int cbase = n0 + wc * 64 + l15;
#pragma unroll
  for (int n = 0; n < 4; ++n) {
    int col = cbase + n * 16;
    float bb = HB ? bias[col] : 0.f;
#pragma unroll
    for (int m = 0; m < MR; ++m) {
      int row0 = rbase + m * 16;
#pragma unroll
      for (int r = 0; r < 4; ++r) {
        size_t idx = (size_t)(row0 + r) * N + col;
        float val = acc[m][n][r];
        if constexpr (EPI == 0) {
          ((u16*)outv)[idx] = f2b(val);
        } else if constexpr (EPI == 1) {
          val += bb;
          val = 0.5f * val * (1.f + erff(val * 0.70710678118654752f));  // exact gelu
          ((u16*)outv)[idx] = f2b(val);
        } else {
          val += bb;
          if (HR) val += res[idx];
          ((float*)outv)[idx] = val;
        }
      }
    }
  }
}

// ---------------------------------------------------------------------------
// Flash attention, bf16. grid (16 q-tiles, 32 b*h), 256 threads = 4 waves,
// each wave owns 32 q-rows. Swapped QK^T (mfma(K,Q) -> S^T, col = q) so the
// k-axis softmax reduce is 2 shfl_xor. LINEAR K/V staging (no swizzle).
// ---------------------------------------------------------------------------
__global__ __launch_bounds__(256) void k_attn(const u16* __restrict__ Q,
                                              const u16* __restrict__ Kg,
                                              const u16* __restrict__ VT,
                                              u16* __restrict__ O) {
  __shared__ __align__(16) char sm[27648];
  char* sK = sm;            // [32][128] bf16 (K rows), 256B rows, linear chunks
  char* sV = sm + 8192;     // [128][32] bf16 (V^T rows), 64B rows, linear chunks
  int t = threadIdx.x, lane = t & 63, w = t >> 6;
  int l15 = lane & 15, q4 = lane >> 4;
  int bh = blockIdx.y;
  int b = bh >> 4, h = bh & 15;
  int q0 = blockIdx.x * 128 + w * 32;
  char* sP = sm + 16384 + w * 2560;             // per-wave P: 32 rows x 80B
  float* sSc = (float*)(sm + 26624 + w * 128);  // per-wave 32 floats
  const float cs = 0.08838834764831845f;  // 1/sqrt(128)
  const u16* Kbase = Kg + (size_t)(b * 2048) * 2048 + h * 128;
  const u16* Vbase = VT + (size_t)(bh * 128) * 2048;
  const u16* Qbase = Q + (size_t)(b * 2048) * 2048 + h * 128;

  bf16x8 qf[2][4];  // B-frags of Q: col q = fn*16+l15, k(d) = kit*32 + q4*8..
#pragma unroll
  for (int fn = 0; fn < 2; ++fn)
#pragma unroll
    for (int kit = 0; kit < 4; ++kit)
      qf[fn][kit] = *(const bf16x8*)(Qbase + (size_t)(q0 + fn * 16 + l15) * 2048 +
                                     kit * 32 + q4 * 8);
  f32x4 oacc[2][8];
#pragma unroll
  for (int fm = 0; fm < 2; ++fm)
#pragma unroll
    for (int fn = 0; fn < 8; ++fn) oacc[fm][fn] = (f32x4){0.f, 0.f, 0.f, 0.f};
  float mrun[2] = {-3e38f, -3e38f}, lrun[2] = {0.f, 0.f};

  int kv_s = t >> 4;   // K staging row (within 16-row half-tile), chunk = t&15
  int d_s = t >> 2;    // V staging row, chunk = t&3

  for (int kv0 = 0; kv0 < 2048; kv0 += 32) {
    __syncthreads();
    G2L(Kbase + (size_t)(kv0 + kv_s) * 2048 + (t & 15) * 8, sK + t * 16);
    G2L(Kbase + (size_t)(kv0 + 16 + kv_s) * 2048 + (t & 15) * 8, sK + 4096 + t * 16);
    G2L(Vbase + (size_t)d_s * 2048 + kv0 + (t & 3) * 8, sV + t * 16);
    G2L(Vbase + (size_t)(64 + d_s) * 2048 + kv0 + (t & 3) * 8, sV + 4096 + t * 16);
    __syncthreads();

    // S^T = K @ Q^T : D[kv][q], frag col = q = l15, row = q4*4+reg (+fm*16)
    f32x4 st[2][2];
#pragma unroll
    for (int fm = 0; fm < 2; ++fm)
#pragma unroll
      for (int fn = 0; fn < 2; ++fn) st[fm][fn] = (f32x4){0.f, 0.f, 0.f, 0.f};
#pragma unroll
    for (int kit = 0; kit < 4; ++kit) {
      int cw = kit * 4 + q4;
      bf16x8 kf0 = *(const bf16x8*)(sK + l15 * 256 + cw * 16);
      bf16x8 kf1 = *(const bf16x8*)(sK + (16 + l15) * 256 + cw * 16);
      st[0][0] = MFMA(kf0, qf[0][kit], st[0][0]);
      st[0][1] = MFMA(kf0, qf[1][kit], st[0][1]);
      st[1][0] = MFMA(kf1, qf[0][kit], st[1][0]);
      st[1][1] = MFMA(kf1, qf[1][kit], st[1][1]);
    }

    // online softmax per q-column (fn picks which q 16-block)
#pragma unroll
    for (int fn = 0; fn < 2; ++fn) {
      float mx = st[0][fn][0];
#pragma unroll
      for (int r = 1; r < 4; ++r) mx = fmaxf(mx, st[0][fn][r]);
#pragma unroll
      for (int r = 0; r < 4; ++r) mx = fmaxf(mx, st[1][fn][r]);
      mx = fmaxf(mx, __shfl_xor(mx, 16));
      mx = fmaxf(mx, __shfl_xor(mx, 32));
      float mnew = fmaxf(mrun[fn], mx);
      float sc = __expf(cs * (mrun[fn] - mnew));
      float psum = 0.f;
      u16 pb[8];
#pragma unroll
      for (int fm = 0; fm < 2; ++fm)
#pragma unroll
        for (int r = 0; r < 4; ++r) {
          float p = __expf(cs * (st[fm][fn][r] - mnew));
          psum += p;
          pb[fm * 4 + r] = f2b(p);
        }
      psum += __shfl_xor(psum, 16);
      psum += __shfl_xor(psum, 32);
      lrun[fn] = lrun[fn] * sc + psum;
      mrun[fn] = mnew;
      int qr = fn * 16 + l15;
      u32x2 w0 = {(u32)pb[0] | ((u32)pb[1] << 16), (u32)pb[2] | ((u32)pb[3] << 16)};
      u32x2 w1 = {(u32)pb[4] | ((u32)pb[5] << 16), (u32)pb[6] | ((u32)pb[7] << 16)};
      *(u32x2*)(sP + qr * 80 + q4 * 8) = w0;        // P[q][k: q4*4..]
      *(u32x2*)(sP + qr * 80 + 32 + q4 * 8) = w1;   // P[q][k: 16+q4*4..]
      if (q4 == 0) sSc[qr] = sc;
    }
    __syncthreads();  // make sP/sSc writes visible

    // rescale accumulators (scale indexed by acc's row q = fm*16 + q4*4 + r)
#pragma unroll
    for (int fm = 0; fm < 2; ++fm) {
      f32x4 sv_ = *(const f32x4*)((char*)sSc + fm * 64 + q4 * 16);
#pragma unroll
      for (int fn = 0; fn < 8; ++fn)
#pragma unroll
        for (int r = 0; r < 4; ++r) oacc[fm][fn][r] *= sv_[r];
    }
    // PV: out[q][d] += P @ V ; A-frag = P rows, B-frag = VT rows
    bf16x8 pa0 = *(const bf16x8*)(sP + l15 * 80 + q4 * 16);
    bf16x8 pa1 = *(const bf16x8*)(sP + (16 + l15) * 80 + q4 * 16);
#pragma unroll
    for (int fn = 0; fn < 8; ++fn) {
      bf16x8 vv = *(const bf16x8*)(sV + (fn * 16 + l15) * 64 + q4 * 16);
      oacc[0][fn] = MFMA(pa0, vv, oacc[0][fn]);
      oacc[1][fn] = MFMA(pa1, vv, oacc[1][fn]);
    }
  }

  if (q4 == 0) { sSc[l15] = lrun[0]; sSc[16 + l15] = lrun[1]; }
  __syncthreads();
  f32x4 lv0 = *(const f32x4*)((char*)sSc + q4 * 16);
  f32x4 lv1 = *(const f32x4*)((char*)sSc + 64 + q4 * 16);
#pragma unroll
  for (int fm = 0; fm < 2; ++fm) {
    f32x4 lv = fm ? lv1 : lv0;
#pragma unroll
    for (int r = 0; r < 4; ++r) {
      int qg = q0 + fm * 16 + q4 * 4 + r;
      float inv = 1.f / lv[r];
#pragma unroll
      for (int fn = 0; fn < 8; ++fn)
        O[(size_t)(b * 2048 + qg) * 2048 + h * 128 + fn * 16 + l15] =
            f2b(oacc[fm][fn][r] * inv);
    }
  }
}

// ---------------------------------------------------------------------------
extern "C" void kernel_launch(void* const* d_in, const int* in_sizes, int n_in,
                              void* d_out, int out_size, void* d_ws, size_t ws_size,
                              hipStream_t stream) {
  (void)in_sizes; (void)n_in; (void)out_size; (void)ws_size;
  const float* x0 = (const float*)d_in[0];
  const int* trait = (const int*)d_in[2];
  const float* wq = (const float*)d_in[3];
  const float* wk = (const float*)d_in[4];
  const float* wv = (const float*)d_in[5];
  const float* wo = (const float*)d_in[6];
  const float* g1 = (const float*)d_in[7];
  const float* b1 = (const float*)d_in[8];
  const float* g2 = (const float*)d_in[9];
  const float* b2 = (const float*)d_in[10];
  const float* rw1 = (const float*)d_in[11];
  const float* rb1 = (const float*)d_in[12];
  const float* rw2 = (const float*)d_in[13];
  const float* rb2 = (const float*)d_in[14];
  const float* rg = (const float*)d_in[15];
  const float* rb = (const float*)d_in[16];
  const float* pemb = (const float*)d_in[17];
  const float* dw = (const float*)d_in[18];
  const float* db = (const float*)d_in[19];
  const float* wg = (const float*)d_in[20];
  const float* wb = (const float*)d_in[21];
  const float* mw1 = (const float*)d_in[22];
  const float* mb1 = (const float*)d_in[23];
  const float* mw2 = (const float*)d_in[24];
  const float* mb2 = (const float*)d_in[25];

  char* ws = (char*)d_ws;
  // arena (bytes): A1 16.78M | B1..B4 4x16.78M | X1 33.55M | H2F 33.55M | WA 33.55M | RV
  u16* A1 = (u16*)ws;
  u16* B1 = (u16*)(ws + 16777216);
  u16* B2 = (u16*)(ws + 33554432);
  u16* B3 = (u16*)(ws + 50331648);
  u16* B4 = (u16*)(ws + 67108864);
  float* X1 = (float*)(ws + 83886080);
  float* H2F = (float*)(ws + 117440512);
  u16* WA = (u16*)(ws + 150994944);
  float* RV = (float*)(ws + 184549376);

  dim3 blk(256), blk8(512);
  // h1 = LN(x0)
  k_ln<false><<<4096, blk, 0, stream>>>(x0, g1, b1, A1, nullptr);
  // q, k, v  (BM=128 -> grid 32x8 = 256 blocks, full chip)
  k_twt<<<dim3(64, 64), blk, 0, stream>>>(wq, WA, 2048, 2048);
  k_gemm8<0, false, false, 128><<<dim3(32, 8), blk8, 0, stream>>>(A1, WA, B1, nullptr, nullptr, 2048, 2048);
  k_twt<<<dim3(64, 64), blk, 0, stream>>>(wk, WA, 2048, 2048);
  k_gemm8<0, false, false, 128><<<dim3(32, 8), blk8, 0, stream>>>(A1, WA, B2, nullptr, nullptr, 2048, 2048);
  k_twt<<<dim3(64, 64), blk, 0, stream>>>(wv, WA, 2048, 2048);
  k_gemm8<0, false, false, 128><<<dim3(32, 8), blk8, 0, stream>>>(A1, WA, B3, nullptr, nullptr, 2048, 2048);
  // per-head V^T, then flash attention -> A1 (bf16)
  k_vt<<<dim3(64, 4, 32), blk, 0, stream>>>(B3, B4);
  k_attn<<<dim3(16, 32), blk, 0, stream>>>(B1, B2, B4, A1);
  // x1 = x0 + attn @ wo
  k_twt<<<dim3(64, 64), blk, 0, stream>>>(wo, WA, 2048, 2048);
  k_gemm8<2, false, true, 128><<<dim3(32, 8), blk8, 0, stream>>>(A1, WA, X1, nullptr, x0, 2048, 2048);
  // h2 = LN(x1) (bf16 + f32)
  k_ln<true><<<4096, blk, 0, stream>>>(X1, g2, b2, A1, H2F);
  // t1 = gelu(h2 @ rw1 + rb1)   (BM=256 -> 16x16 = 256 blocks)
  k_twt<<<dim3(128, 64), blk, 0, stream>>>(rw1, WA, 2048, 4096);
  k_gemm8<1, true, false, 256><<<dim3(16, 16), blk8, 0, stream>>>(A1, WA, B1, rb1, nullptr, 4096, 2048);
  // H2F = h2 + t1 @ rw2 + rb2 (in place), then h3 = LN(.) (bf16 + f32 in place)
  k_twt<<<dim3(64, 128), blk, 0, stream>>>(rw2, WA, 4096, 2048);
  k_gemm8<2, true, true, 128><<<dim3(32, 8), blk8, 0, stream>>>(B1, WA, H2F, rb2, H2F, 2048, 4096);
  k_ln<true><<<4096, blk, 0, stream>>>(H2F, rg, rb, A1, H2F);
  // dec bias row: RV = pemb[trait] @ dw[D:] + db
  hipMemsetAsync(RV, 0, 2048 * sizeof(float), stream);
  k_rowvec<<<dim3(8, 32), blk, 0, stream>>>(pemb, trait, dw, db, RV);
  // H2F = h3 + h3 @ dw[:D] + RV (in place), then h4 = LN(.)
  k_twt<<<dim3(64, 64), blk, 0, stream>>>(dw, WA, 2048, 2048);
  k_gemm8<2, true, true, 128><<<dim3(32, 8), blk8, 0, stream>>>(A1, WA, H2F, RV, H2F, 2048, 2048);
  k_ln<false><<<4096, blk, 0, stream>>>(H2F, wg, wb, A1, nullptr);
  // out = x1 + gelu(h4 @ mw1 + mb1) @ mw2 + mb2   (mw1: BM=256 -> 16x32 = 512)
  k_twt<<<dim3(256, 64), blk, 0, stream>>>(mw1, WA, 2048, 8192);
  k_gemm8<1, true, false, 256><<<dim3(16, 32), blk8, 0, stream>>>(A1, WA, B1, mb1, nullptr, 8192, 2048);
  k_twt<<<dim3(64, 256), blk, 0, stream>>>(mw2, WA, 8192, 2048);
  k_gemm8<2, true, true, 128><<<dim3(32, 8), blk8, 0, stream>>>(B1, WA, (float*)d_out, mb2, X1, 2048, 8192);
}

// Round 5
// 1257.197 us; speedup vs baseline: 1.1639x; 1.1477x over previous
//
#include <hip/hip_runtime.h>
#include <math.h>

typedef __attribute__((ext_vector_type(8))) short bf16x8;   // 8 bf16 in 4 VGPRs (MFMA frag)
typedef __attribute__((ext_vector_type(4))) float f32x4;    // MFMA C/D frag
typedef __attribute__((ext_vector_type(4))) unsigned short u16x4;
typedef __attribute__((ext_vector_type(8))) unsigned short u16x8;
typedef __attribute__((ext_vector_type(2))) unsigned int u32x2;
typedef unsigned short u16;
typedef unsigned int u32;

#define DEV __device__ __forceinline__

DEV u16 f2b(float f) {               // f32 -> bf16 RNE
  u32 u = __builtin_bit_cast(u32, f);
  u += 0x7fffu + ((u >> 16) & 1u);
  return (u16)(u >> 16);
}

#define MFMA(a, b, c) __builtin_amdgcn_mfma_f32_16x16x32_bf16(a, b, c, 0, 0, 0)
// async global->LDS, 16B per lane. LDS dest must be wave-uniform-base + lane*16.
#define G2L(g, l)                                                              \
  __builtin_amdgcn_global_load_lds((__attribute__((address_space(1))) void*)(g), \
                                   (__attribute__((address_space(3))) void*)(l), \
                                   16, 0, 0)

// ---------------------------------------------------------------------------
// LayerNorm over rows of 2048. One block per row, 256 threads x 8 elems.
// ---------------------------------------------------------------------------
template <bool WF32>
__global__ __launch_bounds__(256) void k_ln(const float* __restrict__ in,
                                            const float* __restrict__ gw,
                                            const float* __restrict__ bw,
                                            u16* __restrict__ outb,
                                            float* __restrict__ outf) {
  int row = blockIdx.x, t = threadIdx.x;
  const float* p = in + (size_t)row * 2048 + t * 8;
  float4 v0 = *(const float4*)p;
  float4 v1 = *(const float4*)(p + 4);
  float xv[8] = {v0.x, v0.y, v0.z, v0.w, v1.x, v1.y, v1.z, v1.w};
  float s = 0.f, q = 0.f;
#pragma unroll
  for (int i = 0; i < 8; ++i) { s += xv[i]; q += xv[i] * xv[i]; }
#pragma unroll
  for (int o = 32; o > 0; o >>= 1) {
    s += __shfl_down(s, o);
    q += __shfl_down(q, o);
  }
  __shared__ float rs[4], rq[4];
  int lane = t & 63, w = t >> 6;
  if (lane == 0) { rs[w] = s; rq[w] = q; }
  __syncthreads();
  s = rs[0] + rs[1] + rs[2] + rs[3];
  q = rq[0] + rq[1] + rq[2] + rq[3];
  float mean = s * (1.0f / 2048.0f);
  float inv = rsqrtf(q * (1.0f / 2048.0f) - mean * mean + 1e-5f);
  float4 g0 = *(const float4*)(gw + t * 8);
  float4 g1 = *(const float4*)(gw + t * 8 + 4);
  float4 b0 = *(const float4*)(bw + t * 8);
  float4 b1 = *(const float4*)(bw + t * 8 + 4);
  float gv[8] = {g0.x, g0.y, g0.z, g0.w, g1.x, g1.y, g1.z, g1.w};
  float bv[8] = {b0.x, b0.y, b0.z, b0.w, b1.x, b1.y, b1.z, b1.w};
  float y[8];
  u16x8 ob;
#pragma unroll
  for (int i = 0; i < 8; ++i) {
    y[i] = (xv[i] - mean) * inv * gv[i] + bv[i];
    ob[i] = f2b(y[i]);
  }
  *(u16x8*)(outb + (size_t)row * 2048 + t * 8) = ob;
  if (WF32) {
    float* o = outf + (size_t)row * 2048 + t * 8;
    *(float4*)o = make_float4(y[0], y[1], y[2], y[3]);
    *(float4*)(o + 4) = make_float4(y[4], y[5], y[6], y[7]);
  }
}

// ---------------------------------------------------------------------------
// Transpose + f32->bf16: in K x N f32 row-major -> out N x K bf16 row-major.
// grid (N/32, K/32), 256 threads.
// ---------------------------------------------------------------------------
__global__ __launch_bounds__(256) void k_twt(const float* __restrict__ in,
                                             u16* __restrict__ out, int K, int N) {
  __shared__ float tl[32][33];
  int t = threadIdx.x, r = t >> 3, c = (t & 7) * 4;
  size_t n0 = (size_t)blockIdx.x * 32, k0 = (size_t)blockIdx.y * 32;
  float4 v = *(const float4*)(in + (k0 + r) * N + n0 + c);
  tl[r][c] = v.x; tl[r][c + 1] = v.y; tl[r][c + 2] = v.z; tl[r][c + 3] = v.w;
  __syncthreads();
  u16x4 o = {f2b(tl[c][r]), f2b(tl[c + 1][r]), f2b(tl[c + 2][r]), f2b(tl[c + 3][r])};
  *(u16x4*)(out + (n0 + r) * K + k0 + c) = o;
}

// ---------------------------------------------------------------------------
// V (bf16, [B*S][D] with col = h*128+d) -> VT [(b*16+h)*128 + d][2048]
// grid (64, 4, 32) = (s-tiles, d-tiles, b*h), 256 threads.
// ---------------------------------------------------------------------------
__global__ __launch_bounds__(256) void k_vt(const u16* __restrict__ v,
                                            u16* __restrict__ vt) {
  __shared__ u16 tl[32][36];
  int t = threadIdx.x, r = t >> 3, c = (t & 7) * 4;
  int s0 = blockIdx.x * 32, d0 = blockIdx.y * 32, bh = blockIdx.z;
  int b = bh >> 4, h = bh & 15;
  u16x4 x = *(const u16x4*)(v + (size_t)(b * 2048 + s0 + r) * 2048 + h * 128 + d0 + c);
  tl[r][c] = x[0]; tl[r][c + 1] = x[1]; tl[r][c + 2] = x[2]; tl[r][c + 3] = x[3];
  __syncthreads();
  u16x4 o = {tl[c][r], tl[c + 1][r], tl[c + 2][r], tl[c + 3][r]};
  *(u16x4*)(vt + (size_t)(bh * 128 + d0 + r) * 2048 + s0 + c) = o;
}

// ---------------------------------------------------------------------------
// rowvec[n] = pemb[trait] @ dw[D: , n] (+ db[n]); dec bias row. grid (8, 32).
// ---------------------------------------------------------------------------
__global__ __launch_bounds__(256) void k_rowvec(const float* __restrict__ pemb,
                                                const int* __restrict__ trait,
                                                const float* __restrict__ dw,
                                                const float* __restrict__ db,
                                                float* __restrict__ rv) {
  int n = blockIdx.x * 256 + threadIdx.x;
  int k0 = blockIdx.y * 64;
  const float* pe = pemb + (size_t)trait[0] * 2048;
  float acc = 0.f;
#pragma unroll 4
  for (int k = 0; k < 64; ++k)
    acc = fmaf(pe[k0 + k], dw[(size_t)(2048 + k0 + k) * 2048 + n], acc);
  if (blockIdx.y == 0) acc += db[n];
  atomicAdd(rv + n, acc);
}

// ---------------------------------------------------------------------------
// Phase-split pipelined bf16 GEMM, C = A(MxK) @ Bt(NxK)^T.  (m201-derived)
// BM x 256 tile, BK=64, 512 thr = 8 waves (2Mx4N). 2-slot double buffer;
// slot = [A halves][B halves], half = 16KB (128 rows x 64 cols).
// Per K-tile: 4 phases (BM=256, quadrant (mh,kh), reads 8/4/8/4) or
// 2 phases (BM=128, (kh), reads 8/8); each phase: {ds_read subtile ||
// stage 1-2 half-tiles of kt+1 -> other slot} -> barrier -> setprio(1) ->
// 16 MFMA -> setprio(0) -> barrier. Counted vmcnt ONLY at phase 0 of each
// tile (2 or 4 = own stage in flight; never 0 in steady state). Phase-0
// ds_reads AFTER the barrier (fresh slot; vmcnt is per-wave so the barrier
// publishes all waves' G2L). XOR swizzle pos=chunk^(row&7) on 16B chunks of
// 128B rows; write side pre-swizzles the GLOBAL source (rule 21); ds_read
// conflicts <= 2-way.  EPI: 0=bf16, 1=gelu(x+bias) bf16, 2=f32(+bias)(+res).
// ---------------------------------------------------------------------------
template <int EPI, bool HB, bool HR, int BM>
__global__ __launch_bounds__(512, 2) void k_gemmP(const u16* __restrict__ A,
                                                  const u16* __restrict__ Bt,
                                                  void* __restrict__ outv,
                                                  const float* __restrict__ bias,
                                                  const float* __restrict__ res,
                                                  int N, int K) {
  constexpr int ASLOT = BM * 64 * 2;        // 16KB (BM=128) or 32KB (BM=256)
  constexpr int SLOT = ASLOT + 32768;       // + B 32KB
  constexpr int HA = ASLOT / 16384;         // A halves: 1 or 2
  constexpr int NH = HA + 2;                // halves per K-tile: 3 or 4
  constexpr int MR = BM / 32;               // 4 or 8 m-frags per wave
  __shared__ __align__(16) char smc[2 * SLOT];
  const int t = threadIdx.x, lane = t & 63;
  const int l15 = lane & 15, q4 = (lane >> 4) & 3;
  const int w = t >> 6, wr = w >> 2, wc = w & 3;
  const int m0 = blockIdx.x * BM, n0 = blockIdx.y * 256;

  // staging thread-constants: row-in-inst = t>>3, LDS chunk-pos = t&7,
  // global chunk = pos ^ (row&7)  (pre-swizzled source; LDS stays linear)
  const int srow = t >> 3;
  const int gch = (t & 7) ^ (srow & 7);
  const u16* gA = A + (size_t)(m0 + srow) * K + gch * 8;
  const u16* gB = Bt + (size_t)(n0 + srow) * K + gch * 8;

#define STG(h, kt1, s1)                                                        \
  {                                                                            \
    char* _d = smc + (s1) * SLOT + (h) * 16384 + t * 16;                       \
    const u16* _g = ((h) < HA ? gA + (size_t)((h) * 128) * K                   \
                              : gB + (size_t)(((h) - HA) * 128) * K) +         \
                    (size_t)(kt1) * 64;                                        \
    G2L(_g, _d);                                                               \
    G2L(_g + (size_t)64 * K, _d + 8192);                                       \
  }

  // ds_read byte offsets (sans chunk): row r -> half r>>7, 128B rows
  int pA[MR], pB[4];
#pragma unroll
  for (int m = 0; m < MR; ++m) {
    int r = wr * (BM / 2) + m * 16 + l15;
    pA[m] = (r >> 7) * 16384 + (r & 127) * 128;
  }
#pragma unroll
  for (int n = 0; n < 4; ++n) {
    int r = wc * 64 + n * 16 + l15;
    pB[n] = HA * 16384 + (r >> 7) * 16384 + (r & 127) * 128;
  }
  // chunk term: c = (kh<<2)|q4, pos = c ^ (row&7), row&7 == l15&7
  const int ck0 = ((q4 ^ (l15 & 7)) << 4);
  const int ck1 = (((4 | q4) ^ (l15 & 7)) << 4);

  f32x4 acc[MR][4];
#pragma unroll
  for (int m = 0; m < MR; ++m)
#pragma unroll
    for (int n = 0; n < 4; ++n) acc[m][n] = (f32x4){0.f, 0.f, 0.f, 0.f};

  const int nt = K >> 6;
  // prologue: tile 0 -> slot 0
#pragma unroll
  for (int h = 0; h < NH; ++h) STG(h, 0, 0);

  for (int kt = 0; kt < nt; ++kt) {
    const int s = kt & 1;
    const char* bp = smc + s * SLOT;
    bf16x8 av[4], bv[4];
    if constexpr (BM == 256) {
      // ---- phase 0: (mh0, k0). stage H0(kt+1); counted vmcnt; reads AFTER bar
      if (kt + 1 < nt) {
        STG(0, kt + 1, s ^ 1);
        asm volatile("s_waitcnt vmcnt(2)" ::: "memory");
      } else {
        asm volatile("s_waitcnt vmcnt(0)" ::: "memory");
      }
      asm volatile("s_barrier" ::: "memory");
#pragma unroll
      for (int i = 0; i < 4; ++i) av[i] = *(const bf16x8*)(bp + pA[i] + ck0);
#pragma unroll
      for (int n = 0; n < 4; ++n) bv[n] = *(const bf16x8*)(bp + pB[n] + ck0);
      __builtin_amdgcn_s_setprio(1);
#pragma unroll
      for (int m = 0; m < 4; ++m)
#pragma unroll
        for (int n = 0; n < 4; ++n) acc[m][n] = MFMA(av[m], bv[n], acc[m][n]);
      __builtin_amdgcn_s_setprio(0);
      asm volatile("s_barrier" ::: "memory");
      // ---- phase 1: (mh1, k0)
#pragma unroll
      for (int i = 0; i < 4; ++i) av[i] = *(const bf16x8*)(bp + pA[4 + i] + ck0);
      if (kt + 1 < nt) STG(1, kt + 1, s ^ 1);
      asm volatile("s_barrier" ::: "memory");
      asm volatile("s_waitcnt lgkmcnt(0)" ::: "memory");
      __builtin_amdgcn_sched_barrier(0);
      __builtin_amdgcn_s_setprio(1);
#pragma unroll
      for (int m = 0; m < 4; ++m)
#pragma unroll
        for (int n = 0; n < 4; ++n) acc[4 + m][n] = MFMA(av[m], bv[n], acc[4 + m][n]);
      __builtin_amdgcn_s_setprio(0);
      asm volatile("s_barrier" ::: "memory");
      // ---- phase 2: (mh0, k1)
#pragma unroll
      for (int i = 0; i < 4; ++i) av[i] = *(const bf16x8*)(bp + pA[i] + ck1);
#pragma unroll
      for (int n = 0; n < 4; ++n) bv[n] = *(const bf16x8*)(bp + pB[n] + ck1);
      if (kt + 1 < nt) STG(2, kt + 1, s ^ 1);
      asm volatile("s_barrier" ::: "memory");
      asm volatile("s_waitcnt lgkmcnt(0)" ::: "memory");
      __builtin_amdgcn_sched_barrier(0);
      __builtin_amdgcn_s_setprio(1);
#pragma unroll
      for (int m = 0; m < 4; ++m)
#pragma unroll
        for (int n = 0; n < 4; ++n) acc[m][n] = MFMA(av[m], bv[n], acc[m][n]);
      __builtin_amdgcn_s_setprio(0);
      asm volatile("s_barrier" ::: "memory");
      // ---- phase 3: (mh1, k1)
#pragma unroll
      for (int i = 0; i < 4; ++i) av[i] = *(const bf16x8*)(bp + pA[4 + i] + ck1);
      if (kt + 1 < nt) STG(3, kt + 1, s ^ 1);
      asm volatile("s_barrier" ::: "memory");
      asm volatile("s_waitcnt lgkmcnt(0)" ::: "memory");
      __builtin_amdgcn_sched_barrier(0);
      __builtin_amdgcn_s_setprio(1);
#pragma unroll
      for (int m = 0; m < 4; ++m)
#pragma unroll
        for (int n = 0; n < 4; ++n) acc[4 + m][n] = MFMA(av[m], bv[n], acc[4 + m][n]);
      __builtin_amdgcn_s_setprio(0);
      asm volatile("s_barrier" ::: "memory");
    } else {
      // ---- phase 0: (k0). stage A+B0 of kt+1; counted vmcnt; reads AFTER bar
      if (kt + 1 < nt) {
        STG(0, kt + 1, s ^ 1);
        STG(1, kt + 1, s ^ 1);
        asm volatile("s_waitcnt vmcnt(4)" ::: "memory");
      } else {
        asm volatile("s_waitcnt vmcnt(0)" ::: "memory");
      }
      asm volatile("s_barrier" ::: "memory");
#pragma unroll
      for (int i = 0; i < 4; ++i) av[i] = *(const bf16x8*)(bp + pA[i] + ck0);
#pragma unroll
      for (int n = 0; n < 4; ++n) bv[n] = *(const bf16x8*)(bp + pB[n] + ck0);
      __builtin_amdgcn_s_setprio(1);
#pragma unroll
      for (int m = 0; m < 4; ++m)
#pragma unroll
        for (int n = 0; n < 4; ++n) acc[m][n] = MFMA(av[m], bv[n], acc[m][n]);
      __builtin_amdgcn_s_setprio(0);
      asm volatile("s_barrier" ::: "memory");
      // ---- phase 1: (k1)
#pragma unroll
      for (int i = 0; i < 4; ++i) av[i] = *(const bf16x8*)(bp + pA[i] + ck1);
#pragma unroll
      for (int n = 0; n < 4; ++n) bv[n] = *(const bf16x8*)(bp + pB[n] + ck1);
      if (kt + 1 < nt) STG(2, kt + 1, s ^ 1);
      asm volatile("s_barrier" ::: "memory");
      asm volatile("s_waitcnt lgkmcnt(0)" ::: "memory");
      __builtin_amdgcn_sched_barrier(0);
      __builtin_amdgcn_s_setprio(1);
#pragma unroll
      for (int m = 0; m < 4; ++m)
#pragma unroll
        for (int n = 0; n < 4; ++n) acc[m][n] = MFMA(av[m], bv[n], acc[m][n]);
      __builtin_amdgcn_s_setprio(0);
      asm volatile("s_barrier" ::: "memory");
    }
  }
#undef STG

  // epilogue: C/D frag: col = l15, row = q4*4 + reg (m89-verified mapping)
  int rbase = m0 + wr * (BM / 2) + q4 * 4;
  int cbase = n0 + wc * 64 + l15;
#pragma unroll
  for (int n = 0; n < 4; ++n) {
    int col = cbase + n * 16;
    float bb = HB ? bias[col] : 0.f;
#pragma unroll
    for (int m = 0; m < MR; ++m) {
      int row0 = rbase + m * 16;
#pragma unroll
      for (int r = 0; r < 4; ++r) {
        size_t idx = (size_t)(row0 + r) * N + col;
        float val = acc[m][n][r];
        if constexpr (EPI == 0) {
          ((u16*)outv)[idx] = f2b(val);
        } else if constexpr (EPI == 1) {
          val += bb;
          val = 0.5f * val * (1.f + erff(val * 0.70710678118654752f));  // exact gelu
          ((u16*)outv)[idx] = f2b(val);
        } else {
          val += bb;
          if (HR) val += res[idx];
          ((float*)outv)[idx] = val;
        }
      }
    }
  }
}

// ---------------------------------------------------------------------------
// Flash attention, bf16. grid (16 q-tiles, 32 b*h), 256 threads = 4 waves,
// each wave owns 32 q-rows. Swapped QK^T (mfma(K,Q) -> S^T, col = q) so the
// k-axis softmax reduce is 2 shfl_xor. LINEAR K/V staging (no swizzle).
// ---------------------------------------------------------------------------
__global__ __launch_bounds__(256) void k_attn(const u16* __restrict__ Q,
                                              const u16* __restrict__ Kg,
                                              const u16* __restrict__ VT,
                                              u16* __restrict__ O) {
  __shared__ __align__(16) char sm[27648];
  char* sK = sm;            // [32][128] bf16 (K rows), 256B rows, linear chunks
  char* sV = sm + 8192;     // [128][32] bf16 (V^T rows), 64B rows, linear chunks
  int t = threadIdx.x, lane = t & 63, w = t >> 6;
  int l15 = lane & 15, q4 = lane >> 4;
  int bh = blockIdx.y;
  int b = bh >> 4, h = bh & 15;
  int q0 = blockIdx.x * 128 + w * 32;
  char* sP = sm + 16384 + w * 2560;             // per-wave P: 32 rows x 80B
  float* sSc = (float*)(sm + 26624 + w * 128);  // per-wave 32 floats
  const float cs = 0.08838834764831845f;  // 1/sqrt(128)
  const u16* Kbase = Kg + (size_t)(b * 2048) * 2048 + h * 128;
  const u16* Vbase = VT + (size_t)(bh * 128) * 2048;
  const u16* Qbase = Q + (size_t)(b * 2048) * 2048 + h * 128;

  bf16x8 qf[2][4];  // B-frags of Q: col q = fn*16+l15, k(d) = kit*32 + q4*8..
#pragma unroll
  for (int fn = 0; fn < 2; ++fn)
#pragma unroll
    for (int kit = 0; kit < 4; ++kit)
      qf[fn][kit] = *(const bf16x8*)(Qbase + (size_t)(q0 + fn * 16 + l15) * 2048 +
                                     kit * 32 + q4 * 8);
  f32x4 oacc[2][8];
#pragma unroll
  for (int fm = 0; fm < 2; ++fm)
#pragma unroll
    for (int fn = 0; fn < 8; ++fn) oacc[fm][fn] = (f32x4){0.f, 0.f, 0.f, 0.f};
  float mrun[2] = {-3e38f, -3e38f}, lrun[2] = {0.f, 0.f};

  int kv_s = t >> 4;   // K staging row (within 16-row half-tile), chunk = t&15
  int d_s = t >> 2;    // V staging row, chunk = t&3

  for (int kv0 = 0; kv0 < 2048; kv0 += 32) {
    __syncthreads();
    G2L(Kbase + (size_t)(kv0 + kv_s) * 2048 + (t & 15) * 8, sK + t * 16);
    G2L(Kbase + (size_t)(kv0 + 16 + kv_s) * 2048 + (t & 15) * 8, sK + 4096 + t * 16);
    G2L(Vbase + (size_t)d_s * 2048 + kv0 + (t & 3) * 8, sV + t * 16);
    G2L(Vbase + (size_t)(64 + d_s) * 2048 + kv0 + (t & 3) * 8, sV + 4096 + t * 16);
    __syncthreads();

    // S^T = K @ Q^T : D[kv][q], frag col = q = l15, row = q4*4+reg (+fm*16)
    f32x4 st[2][2];
#pragma unroll
    for (int fm = 0; fm < 2; ++fm)
#pragma unroll
      for (int fn = 0; fn < 2; ++fn) st[fm][fn] = (f32x4){0.f, 0.f, 0.f, 0.f};
#pragma unroll
    for (int kit = 0; kit < 4; ++kit) {
      int cw = kit * 4 + q4;
      bf16x8 kf0 = *(const bf16x8*)(sK + l15 * 256 + cw * 16);
      bf16x8 kf1 = *(const bf16x8*)(sK + (16 + l15) * 256 + cw * 16);
      st[0][0] = MFMA(kf0, qf[0][kit], st[0][0]);
      st[0][1] = MFMA(kf0, qf[1][kit], st[0][1]);
      st[1][0] = MFMA(kf1, qf[0][kit], st[1][0]);
      st[1][1] = MFMA(kf1, qf[1][kit], st[1][1]);
    }

    // online softmax per q-column (fn picks which q 16-block)
#pragma unroll
    for (int fn = 0; fn < 2; ++fn) {
      float mx = st[0][fn][0];
#pragma unroll
      for (int r = 1; r < 4; ++r) mx = fmaxf(mx, st[0][fn][r]);
#pragma unroll
      for (int r = 0; r < 4; ++r) mx = fmaxf(mx, st[1][fn][r]);
      mx = fmaxf(mx, __shfl_xor(mx, 16));
      mx = fmaxf(mx, __shfl_xor(mx, 32));
      float mnew = fmaxf(mrun[fn], mx);
      float sc = __expf(cs * (mrun[fn] - mnew));
      float psum = 0.f;
      u16 pb[8];
#pragma unroll
      for (int fm = 0; fm < 2; ++fm)
#pragma unroll
        for (int r = 0; r < 4; ++r) {
          float p = __expf(cs * (st[fm][fn][r] - mnew));
          psum += p;
          pb[fm * 4 + r] = f2b(p);
        }
      psum += __shfl_xor(psum, 16);
      psum += __shfl_xor(psum, 32);
      lrun[fn] = lrun[fn] * sc + psum;
      mrun[fn] = mnew;
      int qr = fn * 16 + l15;
      u32x2 w0 = {(u32)pb[0] | ((u32)pb[1] << 16), (u32)pb[2] | ((u32)pb[3] << 16)};
      u32x2 w1 = {(u32)pb[4] | ((u32)pb[5] << 16), (u32)pb[6] | ((u32)pb[7] << 16)};
      *(u32x2*)(sP + qr * 80 + q4 * 8) = w0;        // P[q][k: q4*4..]
      *(u32x2*)(sP + qr * 80 + 32 + q4 * 8) = w1;   // P[q][k: 16+q4*4..]
      if (q4 == 0) sSc[qr] = sc;
    }
    __syncthreads();  // make sP/sSc writes visible

    // rescale accumulators (scale indexed by acc's row q = fm*16 + q4*4 + r)
#pragma unroll
    for (int fm = 0; fm < 2; ++fm) {
      f32x4 sv_ = *(const f32x4*)((char*)sSc + fm * 64 + q4 * 16);
#pragma unroll
      for (int fn = 0; fn < 8; ++fn)
#pragma unroll
        for (int r = 0; r < 4; ++r) oacc[fm][fn][r] *= sv_[r];
    }
    // PV: out[q][d] += P @ V ; A-frag = P rows, B-frag = VT rows
    bf16x8 pa0 = *(const bf16x8*)(sP + l15 * 80 + q4 * 16);
    bf16x8 pa1 = *(const bf16x8*)(sP + (16 + l15) * 80 + q4 * 16);
#pragma unroll
    for (int fn = 0; fn < 8; ++fn) {
      bf16x8 vv = *(const bf16x8*)(sV + (fn * 16 + l15) * 64 + q4 * 16);
      oacc[0][fn] = MFMA(pa0, vv, oacc[0][fn]);
      oacc[1][fn] = MFMA(pa1, vv, oacc[1][fn]);
    }
  }

  if (q4 == 0) { sSc[l15] = lrun[0]; sSc[16 + l15] = lrun[1]; }
  __syncthreads();
  f32x4 lv0 = *(const f32x4*)((char*)sSc + q4 * 16);
  f32x4 lv1 = *(const f32x4*)((char*)sSc + 64 + q4 * 16);
#pragma unroll
  for (int fm = 0; fm < 2; ++fm) {
    f32x4 lv = fm ? lv1 : lv0;
#pragma unroll
    for (int r = 0; r < 4; ++r) {
      int qg = q0 + fm * 16 + q4 * 4 + r;
      float inv = 1.f / lv[r];
#pragma unroll
      for (int fn = 0; fn < 8; ++fn)
        O[(size_t)(b * 2048 + qg) * 2048 + h * 128 + fn * 16 + l15] =
            f2b(oacc[fm][fn][r] * inv);
    }
  }
}

// ---------------------------------------------------------------------------
extern "C" void kernel_launch(void* const* d_in, const int* in_sizes, int n_in,
                              void* d_out, int out_size, void* d_ws, size_t ws_size,
                              hipStream_t stream) {
  (void)in_sizes; (void)n_in; (void)out_size; (void)ws_size;
  const float* x0 = (const float*)d_in[0];
  const int* trait = (const int*)d_in[2];
  const float* wq = (const float*)d_in[3];
  const float* wk = (const float*)d_in[4];
  const float* wv = (const float*)d_in[5];
  const float* wo = (const float*)d_in[6];
  const float* g1 = (const float*)d_in[7];
  const float* b1 = (const float*)d_in[8];
  const float* g2 = (const float*)d_in[9];
  const float* b2 = (const float*)d_in[10];
  const float* rw1 = (const float*)d_in[11];
  const float* rb1 = (const float*)d_in[12];
  const float* rw2 = (const float*)d_in[13];
  const float* rb2 = (const float*)d_in[14];
  const float* rg = (const float*)d_in[15];
  const float* rb = (const float*)d_in[16];
  const float* pemb = (const float*)d_in[17];
  const float* dw = (const float*)d_in[18];
  const float* db = (const float*)d_in[19];
  const float* wg = (const float*)d_in[20];
  const float* wb = (const float*)d_in[21];
  const float* mw1 = (const float*)d_in[22];
  const float* mb1 = (const float*)d_in[23];
  const float* mw2 = (const float*)d_in[24];
  const float* mb2 = (const float*)d_in[25];

  char* ws = (char*)d_ws;
  // arena (bytes): A1 16.78M | B1..B4 4x16.78M | X1 33.55M | H2F 33.55M | WA 33.55M | RV
  u16* A1 = (u16*)ws;
  u16* B1 = (u16*)(ws + 16777216);
  u16* B2 = (u16*)(ws + 33554432);
  u16* B3 = (u16*)(ws + 50331648);
  u16* B4 = (u16*)(ws + 67108864);
  float* X1 = (float*)(ws + 83886080);
  float* H2F = (float*)(ws + 117440512);
  u16* WA = (u16*)(ws + 150994944);
  float* RV = (float*)(ws + 184549376);

  dim3 blk(256), blk8(512);
  // h1 = LN(x0)
  k_ln<false><<<4096, blk, 0, stream>>>(x0, g1, b1, A1, nullptr);
  // q, k, v  (BM=128 -> grid 32x8 = 256 blocks)
  k_twt<<<dim3(64, 64), blk, 0, stream>>>(wq, WA, 2048, 2048);
  k_gemmP<0, false, false, 128><<<dim3(32, 8), blk8, 0, stream>>>(A1, WA, B1, nullptr, nullptr, 2048, 2048);
  k_twt<<<dim3(64, 64), blk, 0, stream>>>(wk, WA, 2048, 2048);
  k_gemmP<0, false, false, 128><<<dim3(32, 8), blk8, 0, stream>>>(A1, WA, B2, nullptr, nullptr, 2048, 2048);
  k_twt<<<dim3(64, 64), blk, 0, stream>>>(wv, WA, 2048, 2048);
  k_gemmP<0, false, false, 128><<<dim3(32, 8), blk8, 0, stream>>>(A1, WA, B3, nullptr, nullptr, 2048, 2048);
  // per-head V^T, then flash attention -> A1 (bf16)
  k_vt<<<dim3(64, 4, 32), blk, 0, stream>>>(B3, B4);
  k_attn<<<dim3(16, 32), blk, 0, stream>>>(B1, B2, B4, A1);
  // x1 = x0 + attn @ wo
  k_twt<<<dim3(64, 64), blk, 0, stream>>>(wo, WA, 2048, 2048);
  k_gemmP<2, false, true, 128><<<dim3(32, 8), blk8, 0, stream>>>(A1, WA, X1, nullptr, x0, 2048, 2048);
  // h2 = LN(x1) (bf16 + f32)
  k_ln<true><<<4096, blk, 0, stream>>>(X1, g2, b2, A1, H2F);
  // t1 = gelu(h2 @ rw1 + rb1)   (BM=256 -> 16x16 = 256 blocks)
  k_twt<<<dim3(128, 64), blk, 0, stream>>>(rw1, WA, 2048, 4096);
  k_gemmP<1, true, false, 256><<<dim3(16, 16), blk8, 0, stream>>>(A1, WA, B1, rb1, nullptr, 4096, 2048);
  // H2F = h2 + t1 @ rw2 + rb2 (in place), then h3 = LN(.) (bf16 + f32 in place)
  k_twt<<<dim3(64, 128), blk, 0, stream>>>(rw2, WA, 4096, 2048);
  k_gemmP<2, true, true, 128><<<dim3(32, 8), blk8, 0, stream>>>(B1, WA, H2F, rb2, H2F, 2048, 4096);
  k_ln<true><<<4096, blk, 0, stream>>>(H2F, rg, rb, A1, H2F);
  // dec bias row: RV = pemb[trait] @ dw[D:] + db
  hipMemsetAsync(RV, 0, 2048 * sizeof(float), stream);
  k_rowvec<<<dim3(8, 32), blk, 0, stream>>>(pemb, trait, dw, db, RV);
  // H2F = h3 + h3 @ dw[:D] + RV (in place), then h4 = LN(.)
  k_twt<<<dim3(64, 64), blk, 0, stream>>>(dw, WA, 2048, 2048);
  k_gemmP<2, true, true, 128><<<dim3(32, 8), blk8, 0, stream>>>(A1, WA, H2F, RV, H2F, 2048, 2048);
  k_ln<false><<<4096, blk, 0, stream>>>(H2F, wg, wb, A1, nullptr);
  // out = x1 + gelu(h4 @ mw1 + mb1) @ mw2 + mb2   (mw1: BM=256 -> 16x32 = 512)
  k_twt<<<dim3(256, 64), blk, 0, stream>>>(mw1, WA, 2048, 8192);
  k_gemmP<1, true, false, 256><<<dim3(16, 32), blk8, 0, stream>>>(A1, WA, B1, mb1, nullptr, 8192, 2048);
  k_twt<<<dim3(64, 256), blk, 0, stream>>>(mw2, WA, 8192, 2048);
  k_gemmP<2, true, true, 128><<<dim3(32, 8), blk8, 0, stream>>>(B1, WA, (float*)d_out, mb2, X1, 2048, 8192);
}

// Round 6
// 1221.534 us; speedup vs baseline: 1.1979x; 1.0292x over previous
//
#include <hip/hip_runtime.h>
#include <math.h>

typedef __attribute__((ext_vector_type(8))) short bf16x8;   // 8 bf16 in 4 VGPRs (MFMA frag)
typedef __attribute__((ext_vector_type(4))) float f32x4;    // MFMA C/D frag
typedef __attribute__((ext_vector_type(4))) unsigned short u16x4;
typedef __attribute__((ext_vector_type(8))) unsigned short u16x8;
typedef __attribute__((ext_vector_type(2))) unsigned int u32x2;
typedef unsigned short u16;
typedef unsigned int u32;

#define DEV __device__ __forceinline__

DEV u16 f2b(float f) {               // f32 -> bf16 RNE
  u32 u = __builtin_bit_cast(u32, f);
  u += 0x7fffu + ((u >> 16) & 1u);
  return (u16)(u >> 16);
}

#define MFMA(a, b, c) __builtin_amdgcn_mfma_f32_16x16x32_bf16(a, b, c, 0, 0, 0)
// async global->LDS, 16B per lane. LDS dest must be wave-uniform-base + lane*16.
#define G2L(g, l)                                                              \
  __builtin_amdgcn_global_load_lds((__attribute__((address_space(1))) void*)(g), \
                                   (__attribute__((address_space(3))) void*)(l), \
                                   16, 0, 0)

// ---------------------------------------------------------------------------
// LayerNorm over rows of 2048. One block per row, 256 threads x 8 elems.
// ---------------------------------------------------------------------------
template <bool WF32>
__global__ __launch_bounds__(256) void k_ln(const float* __restrict__ in,
                                            const float* __restrict__ gw,
                                            const float* __restrict__ bw,
                                            u16* __restrict__ outb,
                                            float* __restrict__ outf) {
  int row = blockIdx.x, t = threadIdx.x;
  const float* p = in + (size_t)row * 2048 + t * 8;
  float4 v0 = *(const float4*)p;
  float4 v1 = *(const float4*)(p + 4);
  float xv[8] = {v0.x, v0.y, v0.z, v0.w, v1.x, v1.y, v1.z, v1.w};
  float s = 0.f, q = 0.f;
#pragma unroll
  for (int i = 0; i < 8; ++i) { s += xv[i]; q += xv[i] * xv[i]; }
#pragma unroll
  for (int o = 32; o > 0; o >>= 1) {
    s += __shfl_down(s, o);
    q += __shfl_down(q, o);
  }
  __shared__ float rs[4], rq[4];
  int lane = t & 63, w = t >> 6;
  if (lane == 0) { rs[w] = s; rq[w] = q; }
  __syncthreads();
  s = rs[0] + rs[1] + rs[2] + rs[3];
  q = rq[0] + rq[1] + rq[2] + rq[3];
  float mean = s * (1.0f / 2048.0f);
  float inv = rsqrtf(q * (1.0f / 2048.0f) - mean * mean + 1e-5f);
  float4 g0 = *(const float4*)(gw + t * 8);
  float4 g1 = *(const float4*)(gw + t * 8 + 4);
  float4 b0 = *(const float4*)(bw + t * 8);
  float4 b1 = *(const float4*)(bw + t * 8 + 4);
  float gv[8] = {g0.x, g0.y, g0.z, g0.w, g1.x, g1.y, g1.z, g1.w};
  float bv[8] = {b0.x, b0.y, b0.z, b0.w, b1.x, b1.y, b1.z, b1.w};
  float y[8];
  u16x8 ob;
#pragma unroll
  for (int i = 0; i < 8; ++i) {
    y[i] = (xv[i] - mean) * inv * gv[i] + bv[i];
    ob[i] = f2b(y[i]);
  }
  *(u16x8*)(outb + (size_t)row * 2048 + t * 8) = ob;
  if (WF32) {
    float* o = outf + (size_t)row * 2048 + t * 8;
    *(float4*)o = make_float4(y[0], y[1], y[2], y[3]);
    *(float4*)(o + 4) = make_float4(y[4], y[5], y[6], y[7]);
  }
}

// ---------------------------------------------------------------------------
// Transpose + f32->bf16: in K x N f32 row-major -> out N x K bf16 row-major.
// grid (N/32, K/32), 256 threads.
// ---------------------------------------------------------------------------
__global__ __launch_bounds__(256) void k_twt(const float* __restrict__ in,
                                             u16* __restrict__ out, int K, int N) {
  __shared__ float tl[32][33];
  int t = threadIdx.x, r = t >> 3, c = (t & 7) * 4;
  size_t n0 = (size_t)blockIdx.x * 32, k0 = (size_t)blockIdx.y * 32;
  float4 v = *(const float4*)(in + (k0 + r) * N + n0 + c);
  tl[r][c] = v.x; tl[r][c + 1] = v.y; tl[r][c + 2] = v.z; tl[r][c + 3] = v.w;
  __syncthreads();
  u16x4 o = {f2b(tl[c][r]), f2b(tl[c + 1][r]), f2b(tl[c + 2][r]), f2b(tl[c + 3][r])};
  *(u16x4*)(out + (n0 + r) * K + k0 + c) = o;
}

// ---------------------------------------------------------------------------
// V (bf16, [B*S][D] with col = h*128+d) -> VT [(b*16+h)*128 + d][2048]
// grid (64, 4, 32) = (s-tiles, d-tiles, b*h), 256 threads.
// ---------------------------------------------------------------------------
__global__ __launch_bounds__(256) void k_vt(const u16* __restrict__ v,
                                            u16* __restrict__ vt) {
  __shared__ u16 tl[32][36];
  int t = threadIdx.x, r = t >> 3, c = (t & 7) * 4;
  int s0 = blockIdx.x * 32, d0 = blockIdx.y * 32, bh = blockIdx.z;
  int b = bh >> 4, h = bh & 15;
  u16x4 x = *(const u16x4*)(v + (size_t)(b * 2048 + s0 + r) * 2048 + h * 128 + d0 + c);
  tl[r][c] = x[0]; tl[r][c + 1] = x[1]; tl[r][c + 2] = x[2]; tl[r][c + 3] = x[3];
  __syncthreads();
  u16x4 o = {tl[c][r], tl[c + 1][r], tl[c + 2][r], tl[c + 3][r]};
  *(u16x4*)(vt + (size_t)(bh * 128 + d0 + r) * 2048 + s0 + c) = o;
}

// ---------------------------------------------------------------------------
// rowvec[n] = pemb[trait] @ dw[D: , n] (+ db[n]); dec bias row. grid (8, 32).
// ---------------------------------------------------------------------------
__global__ __launch_bounds__(256) void k_rowvec(const float* __restrict__ pemb,
                                                const int* __restrict__ trait,
                                                const float* __restrict__ dw,
                                                const float* __restrict__ db,
                                                float* __restrict__ rv) {
  int n = blockIdx.x * 256 + threadIdx.x;
  int k0 = blockIdx.y * 64;
  const float* pe = pemb + (size_t)trait[0] * 2048;
  float acc = 0.f;
#pragma unroll 4
  for (int k = 0; k < 64; ++k)
    acc = fmaf(pe[k0 + k], dw[(size_t)(2048 + k0 + k) * 2048 + n], acc);
  if (blockIdx.y == 0) acc += db[n];
  atomicAdd(rv + n, acc);
}

// ---------------------------------------------------------------------------
// Phase-split pipelined bf16 GEMM, C = A(MxK) @ Bt(NxK)^T.  (m201-derived)
// BM x 256 tile, BK=64, 512 thr = 8 waves (2Mx4N). 2-slot double buffer;
// slot = [A halves][B halves], half = 16KB (128 rows x 64 cols).
// Per K-tile: 4 phases (BM=256) or 2 phases (BM=128); each phase: {ds_read
// subtile || stage 1-2 half-tiles of kt+1 -> other slot} -> barrier ->
// setprio(1) -> 16 MFMA -> setprio(0) -> barrier. Counted vmcnt ONLY at
// phase 0 of each tile (own stage in flight; never 0 in steady state).
// XOR swizzle pos=chunk^(row&7) on 16B chunks of 128B rows; write side
// pre-swizzles the GLOBAL source (rule 21); ds_read conflicts <= 2-way.
// EPI: 0=bf16, 1=gelu(x+bias) bf16, 2=f32(+bias)(+res).
// ---------------------------------------------------------------------------
template <int EPI, bool HB, bool HR, int BM>
__global__ __launch_bounds__(512, 2) void k_gemmP(const u16* __restrict__ A,
                                                  const u16* __restrict__ Bt,
                                                  void* __restrict__ outv,
                                                  const float* __restrict__ bias,
                                                  const float* __restrict__ res,
                                                  int N, int K) {
  constexpr int ASLOT = BM * 64 * 2;        // 16KB (BM=128) or 32KB (BM=256)
  constexpr int SLOT = ASLOT + 32768;       // + B 32KB
  constexpr int HA = ASLOT / 16384;         // A halves: 1 or 2
  constexpr int NH = HA + 2;                // halves per K-tile: 3 or 4
  constexpr int MR = BM / 32;               // 4 or 8 m-frags per wave
  __shared__ __align__(16) char smc[2 * SLOT];
  const int t = threadIdx.x, lane = t & 63;
  const int l15 = lane & 15, q4 = (lane >> 4) & 3;
  const int w = t >> 6, wr = w >> 2, wc = w & 3;
  const int m0 = blockIdx.x * BM, n0 = blockIdx.y * 256;

  // staging thread-constants: row-in-inst = t>>3, LDS chunk-pos = t&7,
  // global chunk = pos ^ (row&7)  (pre-swizzled source; LDS stays linear)
  const int srow = t >> 3;
  const int gch = (t & 7) ^ (srow & 7);
  const u16* gA = A + (size_t)(m0 + srow) * K + gch * 8;
  const u16* gB = Bt + (size_t)(n0 + srow) * K + gch * 8;

#define STG(h, kt1, s1)                                                        \
  {                                                                            \
    char* _d = smc + (s1) * SLOT + (h) * 16384 + t * 16;                       \
    const u16* _g = ((h) < HA ? gA + (size_t)((h) * 128) * K                   \
                              : gB + (size_t)(((h) - HA) * 128) * K) +         \
                    (size_t)(kt1) * 64;                                        \
    G2L(_g, _d);                                                               \
    G2L(_g + (size_t)64 * K, _d + 8192);                                       \
  }

  // ds_read byte offsets (sans chunk): row r -> half r>>7, 128B rows
  int pA[MR], pB[4];
#pragma unroll
  for (int m = 0; m < MR; ++m) {
    int r = wr * (BM / 2) + m * 16 + l15;
    pA[m] = (r >> 7) * 16384 + (r & 127) * 128;
  }
#pragma unroll
  for (int n = 0; n < 4; ++n) {
    int r = wc * 64 + n * 16 + l15;
    pB[n] = HA * 16384 + (r >> 7) * 16384 + (r & 127) * 128;
  }
  // chunk term: c = (kh<<2)|q4, pos = c ^ (row&7), row&7 == l15&7
  const int ck0 = ((q4 ^ (l15 & 7)) << 4);
  const int ck1 = (((4 | q4) ^ (l15 & 7)) << 4);

  f32x4 acc[MR][4];
#pragma unroll
  for (int m = 0; m < MR; ++m)
#pragma unroll
    for (int n = 0; n < 4; ++n) acc[m][n] = (f32x4){0.f, 0.f, 0.f, 0.f};

  const int nt = K >> 6;
  // prologue: tile 0 -> slot 0
#pragma unroll
  for (int h = 0; h < NH; ++h) STG(h, 0, 0);

  for (int kt = 0; kt < nt; ++kt) {
    const int s = kt & 1;
    const char* bp = smc + s * SLOT;
    bf16x8 av[4], bv[4];
    if constexpr (BM == 256) {
      // ---- phase 0: (mh0, k0). stage H0(kt+1); counted vmcnt; reads AFTER bar
      if (kt + 1 < nt) {
        STG(0, kt + 1, s ^ 1);
        asm volatile("s_waitcnt vmcnt(2)" ::: "memory");
      } else {
        asm volatile("s_waitcnt vmcnt(0)" ::: "memory");
      }
      asm volatile("s_barrier" ::: "memory");
#pragma unroll
      for (int i = 0; i < 4; ++i) av[i] = *(const bf16x8*)(bp + pA[i] + ck0);
#pragma unroll
      for (int n = 0; n < 4; ++n) bv[n] = *(const bf16x8*)(bp + pB[n] + ck0);
      __builtin_amdgcn_s_setprio(1);
#pragma unroll
      for (int m = 0; m < 4; ++m)
#pragma unroll
        for (int n = 0; n < 4; ++n) acc[m][n] = MFMA(av[m], bv[n], acc[m][n]);
      __builtin_amdgcn_s_setprio(0);
      asm volatile("s_barrier" ::: "memory");
      // ---- phase 1: (mh1, k0)
#pragma unroll
      for (int i = 0; i < 4; ++i) av[i] = *(const bf16x8*)(bp + pA[4 + i] + ck0);
      if (kt + 1 < nt) STG(1, kt + 1, s ^ 1);
      asm volatile("s_barrier" ::: "memory");
      asm volatile("s_waitcnt lgkmcnt(0)" ::: "memory");
      __builtin_amdgcn_sched_barrier(0);
      __builtin_amdgcn_s_setprio(1);
#pragma unroll
      for (int m = 0; m < 4; ++m)
#pragma unroll
        for (int n = 0; n < 4; ++n) acc[4 + m][n] = MFMA(av[m], bv[n], acc[4 + m][n]);
      __builtin_amdgcn_s_setprio(0);
      asm volatile("s_barrier" ::: "memory");
      // ---- phase 2: (mh0, k1)
#pragma unroll
      for (int i = 0; i < 4; ++i) av[i] = *(const bf16x8*)(bp + pA[i] + ck1);
#pragma unroll
      for (int n = 0; n < 4; ++n) bv[n] = *(const bf16x8*)(bp + pB[n] + ck1);
      if (kt + 1 < nt) STG(2, kt + 1, s ^ 1);
      asm volatile("s_barrier" ::: "memory");
      asm volatile("s_waitcnt lgkmcnt(0)" ::: "memory");
      __builtin_amdgcn_sched_barrier(0);
      __builtin_amdgcn_s_setprio(1);
#pragma unroll
      for (int m = 0; m < 4; ++m)
#pragma unroll
        for (int n = 0; n < 4; ++n) acc[m][n] = MFMA(av[m], bv[n], acc[m][n]);
      __builtin_amdgcn_s_setprio(0);
      asm volatile("s_barrier" ::: "memory");
      // ---- phase 3: (mh1, k1)
#pragma unroll
      for (int i = 0; i < 4; ++i) av[i] = *(const bf16x8*)(bp + pA[4 + i] + ck1);
      if (kt + 1 < nt) STG(3, kt + 1, s ^ 1);
      asm volatile("s_barrier" ::: "memory");
      asm volatile("s_waitcnt lgkmcnt(0)" ::: "memory");
      __builtin_amdgcn_sched_barrier(0);
      __builtin_amdgcn_s_setprio(1);
#pragma unroll
      for (int m = 0; m < 4; ++m)
#pragma unroll
        for (int n = 0; n < 4; ++n) acc[4 + m][n] = MFMA(av[m], bv[n], acc[4 + m][n]);
      __builtin_amdgcn_s_setprio(0);
      asm volatile("s_barrier" ::: "memory");
    } else {
      // ---- phase 0: (k0). stage A+B0 of kt+1; counted vmcnt; reads AFTER bar
      if (kt + 1 < nt) {
        STG(0, kt + 1, s ^ 1);
        STG(1, kt + 1, s ^ 1);
        asm volatile("s_waitcnt vmcnt(4)" ::: "memory");
      } else {
        asm volatile("s_waitcnt vmcnt(0)" ::: "memory");
      }
      asm volatile("s_barrier" ::: "memory");
#pragma unroll
      for (int i = 0; i < 4; ++i) av[i] = *(const bf16x8*)(bp + pA[i] + ck0);
#pragma unroll
      for (int n = 0; n < 4; ++n) bv[n] = *(const bf16x8*)(bp + pB[n] + ck0);
      __builtin_amdgcn_s_setprio(1);
#pragma unroll
      for (int m = 0; m < 4; ++m)
#pragma unroll
        for (int n = 0; n < 4; ++n) acc[m][n] = MFMA(av[m], bv[n], acc[m][n]);
      __builtin_amdgcn_s_setprio(0);
      asm volatile("s_barrier" ::: "memory");
      // ---- phase 1: (k1)
#pragma unroll
      for (int i = 0; i < 4; ++i) av[i] = *(const bf16x8*)(bp + pA[i] + ck1);
#pragma unroll
      for (int n = 0; n < 4; ++n) bv[n] = *(const bf16x8*)(bp + pB[n] + ck1);
      if (kt + 1 < nt) STG(2, kt + 1, s ^ 1);
      asm volatile("s_barrier" ::: "memory");
      asm volatile("s_waitcnt lgkmcnt(0)" ::: "memory");
      __builtin_amdgcn_sched_barrier(0);
      __builtin_amdgcn_s_setprio(1);
#pragma unroll
      for (int m = 0; m < 4; ++m)
#pragma unroll
        for (int n = 0; n < 4; ++n) acc[m][n] = MFMA(av[m], bv[n], acc[m][n]);
      __builtin_amdgcn_s_setprio(0);
      asm volatile("s_barrier" ::: "memory");
    }
  }
#undef STG

  // epilogue: C/D frag: col = l15, row = q4*4 + reg (m89-verified mapping)
  int rbase = m0 + wr * (BM / 2) + q4 * 4;
  int cbase = n0 + wc * 64 + l15;
#pragma unroll
  for (int n = 0; n < 4; ++n) {
    int col = cbase + n * 16;
    float bb = HB ? bias[col] : 0.f;
#pragma unroll
    for (int m = 0; m < MR; ++m) {
      int row0 = rbase + m * 16;
#pragma unroll
      for (int r = 0; r < 4; ++r) {
        size_t idx = (size_t)(row0 + r) * N + col;
        float val = acc[m][n][r];
        if constexpr (EPI == 0) {
          ((u16*)outv)[idx] = f2b(val);
        } else if constexpr (EPI == 1) {
          val += bb;
          val = 0.5f * val * (1.f + erff(val * 0.70710678118654752f));  // exact gelu
          ((u16*)outv)[idx] = f2b(val);
        } else {
          val += bb;
          if (HR) val += res[idx];
          ((float*)outv)[idx] = val;
        }
      }
    }
  }
}

// ---------------------------------------------------------------------------
// Flash attention, bf16. grid (16 q-tiles, 32 b*h), 256 threads = 4 waves,
// each wave owns 32 q-rows. Swapped QK^T (mfma(K,Q) -> S^T, col = q) so the
// k-axis softmax reduce is 2 shfl_xor.
// K staging XOR-SWIZZLED (rule 21: pre-swizzled GLOBAL source, linear LDS
// dest, read at pos = cw ^ (row&7)): kills the 16-way ds_read_b128 conflict
// (256B rows -> bank depends only on byte-within-row; uniform cw = 16-way).
// V/P stay linear (measured <=2-way, free per m136).
// ---------------------------------------------------------------------------
__global__ __launch_bounds__(256) void k_attn(const u16* __restrict__ Q,
                                              const u16* __restrict__ Kg,
                                              const u16* __restrict__ VT,
                                              u16* __restrict__ O) {
  __shared__ __align__(16) char sm[27648];
  char* sK = sm;            // [32][128] bf16 (K rows), 256B rows, swizzled chunks
  char* sV = sm + 8192;     // [128][32] bf16 (V^T rows), 64B rows, linear chunks
  int t = threadIdx.x, lane = t & 63, w = t >> 6;
  int l15 = lane & 15, q4 = lane >> 4;
  int bh = blockIdx.y;
  int b = bh >> 4, h = bh & 15;
  int q0 = blockIdx.x * 128 + w * 32;
  char* sP = sm + 16384 + w * 2560;             // per-wave P: 32 rows x 80B
  float* sSc = (float*)(sm + 26624 + w * 128);  // per-wave 32 floats
  const float cs = 0.08838834764831845f;  // 1/sqrt(128)
  const u16* Kbase = Kg + (size_t)(b * 2048) * 2048 + h * 128;
  const u16* Vbase = VT + (size_t)(bh * 128) * 2048;
  const u16* Qbase = Q + (size_t)(b * 2048) * 2048 + h * 128;

  bf16x8 qf[2][4];  // B-frags of Q: col q = fn*16+l15, k(d) = kit*32 + q4*8..
#pragma unroll
  for (int fn = 0; fn < 2; ++fn)
#pragma unroll
    for (int kit = 0; kit < 4; ++kit)
      qf[fn][kit] = *(const bf16x8*)(Qbase + (size_t)(q0 + fn * 16 + l15) * 2048 +
                                     kit * 32 + q4 * 8);
  f32x4 oacc[2][8];
#pragma unroll
  for (int fm = 0; fm < 2; ++fm)
#pragma unroll
    for (int fn = 0; fn < 8; ++fn) oacc[fm][fn] = (f32x4){0.f, 0.f, 0.f, 0.f};
  float mrun[2] = {-3e38f, -3e38f}, lrun[2] = {0.f, 0.f};

  int kv_s = t >> 4;   // K staging row (within 16-row half-tile)
  // K pre-swizzled global chunk: LDS pos (t&15) of row kv_s holds global
  // chunk (t&15) ^ (kv_s&7); (16+kv_s)&7 == kv_s&7 so both halves share it.
  int gcK = ((t & 15) ^ ((t >> 4) & 7)) * 8;
  int d_s = t >> 2;    // V staging row, chunk = t&3 (linear)
  int kx = l15 & 7;    // K read-side XOR (row&7 == l15&7 for rows l15, 16+l15)

  for (int kv0 = 0; kv0 < 2048; kv0 += 32) {
    __syncthreads();
    G2L(Kbase + (size_t)(kv0 + kv_s) * 2048 + gcK, sK + t * 16);
    G2L(Kbase + (size_t)(kv0 + 16 + kv_s) * 2048 + gcK, sK + 4096 + t * 16);
    G2L(Vbase + (size_t)d_s * 2048 + kv0 + (t & 3) * 8, sV + t * 16);
    G2L(Vbase + (size_t)(64 + d_s) * 2048 + kv0 + (t & 3) * 8, sV + 4096 + t * 16);
    __syncthreads();

    // S^T = K @ Q^T : D[kv][q], frag col = q = l15, row = q4*4+reg (+fm*16)
    f32x4 st[2][2];
#pragma unroll
    for (int fm = 0; fm < 2; ++fm)
#pragma unroll
      for (int fn = 0; fn < 2; ++fn) st[fm][fn] = (f32x4){0.f, 0.f, 0.f, 0.f};
#pragma unroll
    for (int kit = 0; kit < 4; ++kit) {
      int cw = kit * 4 + q4;
      bf16x8 kf0 = *(const bf16x8*)(sK + l15 * 256 + ((cw ^ kx) * 16));
      bf16x8 kf1 = *(const bf16x8*)(sK + (16 + l15) * 256 + ((cw ^ kx) * 16));
      st[0][0] = MFMA(kf0, qf[0][kit], st[0][0]);
      st[0][1] = MFMA(kf0, qf[1][kit], st[0][1]);
      st[1][0] = MFMA(kf1, qf[0][kit], st[1][0]);
      st[1][1] = MFMA(kf1, qf[1][kit], st[1][1]);
    }

    // online softmax per q-column (fn picks which q 16-block)
#pragma unroll
    for (int fn = 0; fn < 2; ++fn) {
      float mx = st[0][fn][0];
#pragma unroll
      for (int r = 1; r < 4; ++r) mx = fmaxf(mx, st[0][fn][r]);
#pragma unroll
      for (int r = 0; r < 4; ++r) mx = fmaxf(mx, st[1][fn][r]);
      mx = fmaxf(mx, __shfl_xor(mx, 16));
      mx = fmaxf(mx, __shfl_xor(mx, 32));
      float mnew = fmaxf(mrun[fn], mx);
      float sc = __expf(cs * (mrun[fn] - mnew));
      float psum = 0.f;
      u16 pb[8];
#pragma unroll
      for (int fm = 0; fm < 2; ++fm)
#pragma unroll
        for (int r = 0; r < 4; ++r) {
          float p = __expf(cs * (st[fm][fn][r] - mnew));
          psum += p;
          pb[fm * 4 + r] = f2b(p);
        }
      psum += __shfl_xor(psum, 16);
      psum += __shfl_xor(psum, 32);
      lrun[fn] = lrun[fn] * sc + psum;
      mrun[fn] = mnew;
      int qr = fn * 16 + l15;
      u32x2 w0 = {(u32)pb[0] | ((u32)pb[1] << 16), (u32)pb[2] | ((u32)pb[3] << 16)};
      u32x2 w1 = {(u32)pb[4] | ((u32)pb[5] << 16), (u32)pb[6] | ((u32)pb[7] << 16)};
      *(u32x2*)(sP + qr * 80 + q4 * 8) = w0;        // P[q][k: q4*4..]
      *(u32x2*)(sP + qr * 80 + 32 + q4 * 8) = w1;   // P[q][k: 16+q4*4..]
      if (q4 == 0) sSc[qr] = sc;
    }
    __syncthreads();  // make sP/sSc writes visible

    // rescale accumulators (scale indexed by acc's row q = fm*16 + q4*4 + r)
#pragma unroll
    for (int fm = 0; fm < 2; ++fm) {
      f32x4 sv_ = *(const f32x4*)((char*)sSc + fm * 64 + q4 * 16);
#pragma unroll
      for (int fn = 0; fn < 8; ++fn)
#pragma unroll
        for (int r = 0; r < 4; ++r) oacc[fm][fn][r] *= sv_[r];
    }
    // PV: out[q][d] += P @ V ; A-frag = P rows, B-frag = VT rows
    bf16x8 pa0 = *(const bf16x8*)(sP + l15 * 80 + q4 * 16);
    bf16x8 pa1 = *(const bf16x8*)(sP + (16 + l15) * 80 + q4 * 16);
#pragma unroll
    for (int fn = 0; fn < 8; ++fn) {
      bf16x8 vv = *(const bf16x8*)(sV + (fn * 16 + l15) * 64 + q4 * 16);
      oacc[0][fn] = MFMA(pa0, vv, oacc[0][fn]);
      oacc[1][fn] = MFMA(pa1, vv, oacc[1][fn]);
    }
  }

  if (q4 == 0) { sSc[l15] = lrun[0]; sSc[16 + l15] = lrun[1]; }
  __syncthreads();
  f32x4 lv0 = *(const f32x4*)((char*)sSc + q4 * 16);
  f32x4 lv1 = *(const f32x4*)((char*)sSc + 64 + q4 * 16);
#pragma unroll
  for (int fm = 0; fm < 2; ++fm) {
    f32x4 lv = fm ? lv1 : lv0;
#pragma unroll
    for (int r = 0; r < 4; ++r) {
      int qg = q0 + fm * 16 + q4 * 4 + r;
      float inv = 1.f / lv[r];
#pragma unroll
      for (int fn = 0; fn < 8; ++fn)
        O[(size_t)(b * 2048 + qg) * 2048 + h * 128 + fn * 16 + l15] =
            f2b(oacc[fm][fn][r] * inv);
    }
  }
}

// ---------------------------------------------------------------------------
extern "C" void kernel_launch(void* const* d_in, const int* in_sizes, int n_in,
                              void* d_out, int out_size, void* d_ws, size_t ws_size,
                              hipStream_t stream) {
  (void)in_sizes; (void)n_in; (void)out_size; (void)ws_size;
  const float* x0 = (const float*)d_in[0];
  const int* trait = (const int*)d_in[2];
  const float* wq = (const float*)d_in[3];
  const float* wk = (const float*)d_in[4];
  const float* wv = (const float*)d_in[5];
  const float* wo = (const float*)d_in[6];
  const float* g1 = (const float*)d_in[7];
  const float* b1 = (const float*)d_in[8];
  const float* g2 = (const float*)d_in[9];
  const float* b2 = (const float*)d_in[10];
  const float* rw1 = (const float*)d_in[11];
  const float* rb1 = (const float*)d_in[12];
  const float* rw2 = (const float*)d_in[13];
  const float* rb2 = (const float*)d_in[14];
  const float* rg = (const float*)d_in[15];
  const float* rb = (const float*)d_in[16];
  const float* pemb = (const float*)d_in[17];
  const float* dw = (const float*)d_in[18];
  const float* db = (const float*)d_in[19];
  const float* wg = (const float*)d_in[20];
  const float* wb = (const float*)d_in[21];
  const float* mw1 = (const float*)d_in[22];
  const float* mb1 = (const float*)d_in[23];
  const float* mw2 = (const float*)d_in[24];
  const float* mb2 = (const float*)d_in[25];

  char* ws = (char*)d_ws;
  // arena (bytes): A1 16.78M | B1..B4 4x16.78M | X1 33.55M | H2F 33.55M | WA 33.55M | RV
  u16* A1 = (u16*)ws;
  u16* B1 = (u16*)(ws + 16777216);
  u16* B2 = (u16*)(ws + 33554432);
  u16* B3 = (u16*)(ws + 50331648);
  u16* B4 = (u16*)(ws + 67108864);
  float* X1 = (float*)(ws + 83886080);
  float* H2F = (float*)(ws + 117440512);
  u16* WA = (u16*)(ws + 150994944);
  float* RV = (float*)(ws + 184549376);

  dim3 blk(256), blk8(512);
  // h1 = LN(x0)
  k_ln<false><<<4096, blk, 0, stream>>>(x0, g1, b1, A1, nullptr);
  // q, k, v  (BM=128 -> grid 32x8 = 256 blocks)
  k_twt<<<dim3(64, 64), blk, 0, stream>>>(wq, WA, 2048, 2048);
  k_gemmP<0, false, false, 128><<<dim3(32, 8), blk8, 0, stream>>>(A1, WA, B1, nullptr, nullptr, 2048, 2048);
  k_twt<<<dim3(64, 64), blk, 0, stream>>>(wk, WA, 2048, 2048);
  k_gemmP<0, false, false, 128><<<dim3(32, 8), blk8, 0, stream>>>(A1, WA, B2, nullptr, nullptr, 2048, 2048);
  k_twt<<<dim3(64, 64), blk, 0, stream>>>(wv, WA, 2048, 2048);
  k_gemmP<0, false, false, 128><<<dim3(32, 8), blk8, 0, stream>>>(A1, WA, B3, nullptr, nullptr, 2048, 2048);
  // per-head V^T, then flash attention -> A1 (bf16)
  k_vt<<<dim3(64, 4, 32), blk, 0, stream>>>(B3, B4);
  k_attn<<<dim3(16, 32), blk, 0, stream>>>(B1, B2, B4, A1);
  // x1 = x0 + attn @ wo
  k_twt<<<dim3(64, 64), blk, 0, stream>>>(wo, WA, 2048, 2048);
  k_gemmP<2, false, true, 128><<<dim3(32, 8), blk8, 0, stream>>>(A1, WA, X1, nullptr, x0, 2048, 2048);
  // h2 = LN(x1) (bf16 + f32)
  k_ln<true><<<4096, blk, 0, stream>>>(X1, g2, b2, A1, H2F);
  // t1 = gelu(h2 @ rw1 + rb1)   (BM=256 -> 16x16 = 256 blocks)
  k_twt<<<dim3(128, 64), blk, 0, stream>>>(rw1, WA, 2048, 4096);
  k_gemmP<1, true, false, 256><<<dim3(16, 16), blk8, 0, stream>>>(A1, WA, B1, rb1, nullptr, 4096, 2048);
  // H2F = h2 + t1 @ rw2 + rb2 (in place), then h3 = LN(.) (bf16 + f32 in place)
  k_twt<<<dim3(64, 128), blk, 0, stream>>>(rw2, WA, 4096, 2048);
  k_gemmP<2, true, true, 128><<<dim3(32, 8), blk8, 0, stream>>>(B1, WA, H2F, rb2, H2F, 2048, 4096);
  k_ln<true><<<4096, blk, 0, stream>>>(H2F, rg, rb, A1, H2F);
  // dec bias row: RV = pemb[trait] @ dw[D:] + db
  hipMemsetAsync(RV, 0, 2048 * sizeof(float), stream);
  k_rowvec<<<dim3(8, 32), blk, 0, stream>>>(pemb, trait, dw, db, RV);
  // H2F = h3 + h3 @ dw[:D] + RV (in place), then h4 = LN(.)
  k_twt<<<dim3(64, 64), blk, 0, stream>>>(dw, WA, 2048, 2048);
  k_gemmP<2, true, true, 128><<<dim3(32, 8), blk8, 0, stream>>>(A1, WA, H2F, RV, H2F, 2048, 2048);
  k_ln<false><<<4096, blk, 0, stream>>>(H2F, wg, wb, A1, nullptr);
  // out = x1 + gelu(h4 @ mw1 + mb1) @ mw2 + mb2   (mw1: BM=256 -> 16x32 = 512)
  k_twt<<<dim3(256, 64), blk, 0, stream>>>(mw1, WA, 2048, 8192);
  k_gemmP<1, true, false, 256><<<dim3(16, 32), blk8, 0, stream>>>(A1, WA, B1, mb1, nullptr, 8192, 2048);
  k_twt<<<dim3(64, 256), blk, 0, stream>>>(mw2, WA, 8192, 2048);
  k_gemmP<2, true, true, 128><<<dim3(32, 8), blk8, 0, stream>>>(B1, WA, (float*)d_out, mb2, X1, 2048, 8192);
}